// Round 1
// baseline (1829.600 us; speedup 1.0000x reference)
//
#include <hip/hip_runtime.h>
#include <math.h>

#pragma clang fp contract(off)

#define NIMG 16
#define NP   8732
#define NCLS 81
#define NFG  80
#define KTOP 1000
#define KPAD 1024
#define DETS 100
#define CAPMAX 166912          // >= 19*8732 (hard bound: <=19 softmax scores can exceed 0.05)
#define BASEBITS 0x3D000000u   // float bits of 0.03125, below 0.05 threshold; low 13 bits zero

// ---- workspace layout (bytes) ----
#define OFF_BOXES  0u            // [NIMG][NP][4] f32  = 2,235,392
#define OFF_CNT    2235392u      // [NIMG] u32 (256B)
#define OFF_TOPK   2235648u      // [NIMG][KPAD] u64   = 131,072
#define OFF_CSCORE 2366720u      // [NIMG][KPAD] f32
#define OFF_CLABEL 2432256u      // [NIMG][KPAD] i32
#define OFF_CBOX   2497792u      // [NIMG][KPAD] float4
#define OFF_COFFS  2759936u      // [NIMG][KPAD] float4
#define OFF_CAREA  3022080u      // [NIMG][KPAD] f32
#define OFF_VALIDW 3087616u      // [NIMG][16] u64
#define OFF_MASK   3089664u      // [NIMG][KPAD][16] u64 = 2,097,152
#define OFF_CAND   5186816u      // [NIMG][cap] u64

typedef unsigned long long u64;
typedef unsigned int u32;

// ============================================================ kernel 1
// one wave per prior: decode box, softmax over 81 classes, compact candidates
__global__ __launch_bounds__(256) void k_decode(
    const float* __restrict__ logits, const float* __restrict__ rel,
    const float* __restrict__ priors, const int* __restrict__ tsz,
    float* __restrict__ boxes_out, u64* __restrict__ cand,
    u32* __restrict__ cnt, int cap)
{
#pragma clang fp contract(off)
    int wave = blockIdx.x * 4 + (threadIdx.x >> 6);
    int lid  = threadIdx.x & 63;
    int b = wave / NP, p = wave - b * NP;
    size_t lbase = (size_t)(b * NP + p) * NCLS;
    float x0 = logits[lbase + lid];
    float x1 = (lid < 17) ? logits[lbase + 64 + lid] : -3.4e38f;

    int size_ok = 0;
    if (lid == 0) {
        const float* pr = priors + (size_t)p * 4;
        const float* rl = rel + (size_t)(b * NP + p) * 4;
        float W = (float)tsz[b * 2 + 1], H = (float)tsz[b * 2 + 0];
        float cx = pr[0] + (rl[0] * 0.1f) * pr[2];
        float cy = pr[1] + (rl[1] * 0.1f) * pr[3];
        float w_ = pr[2] * expf(rl[2] * 0.2f);
        float h_ = pr[3] * expf(rl[3] * 0.2f);
        float sx1 = (cx - 0.5f * w_) * W, sy1 = (cy - 0.5f * h_) * H;
        float sx2 = (cx + 0.5f * w_) * W, sy2 = (cy + 0.5f * h_) * H;
        float4 bx = make_float4(sx1, sy1, sx2, sy2);
        ((float4*)boxes_out)[b * NP + p] = bx;
        size_ok = ((sx2 - sx1) >= 0.01f) && ((sy2 - sy1) >= 0.01f);
    }
    size_ok = __shfl(size_ok, 0);

    float m = fmaxf(x0, x1);
    for (int d = 1; d < 64; d <<= 1) m = fmaxf(m, __shfl_xor(m, d));
    float e0 = expf(x0 - m);
    float e1 = (lid < 17) ? expf(x1 - m) : 0.0f;
    float s = e0 + e1;
    for (int d = 1; d < 64; d <<= 1) s += __shfl_xor(s, d);
    float sc0 = e0 / s;
    float sc1 = e1 / s;

    bool v0 = (lid >= 1) && size_ok && (sc0 > 0.05f);           // classes 1..63
    bool v1 = (lid <= 16) && size_ok && (sc1 > 0.05f);          // classes 64..80
    u64 b0 = __ballot(v0), b1 = __ballot(v1);
    int tot = __popcll(b0) + __popcll(b1);
    u32 base = 0;
    if (lid == 0 && tot) base = atomicAdd(cnt + b, (u32)tot);
    base = (u32)__shfl((int)base, 0);
    u64 mlt = (1ULL << lid) - 1ULL;
    u64* cb = cand + (size_t)b * cap;
    if (v0) {
        u32 pos = base + (u32)__popcll(b0 & mlt);
        u32 flat = (u32)p * NFG + (u32)(lid - 1);
        if ((int)pos < cap)
            cb[pos] = ((u64)__float_as_uint(sc0) << 32) | (u64)(0xFFFFFFFFu - flat);
    }
    if (v1) {
        u32 pos = base + (u32)__popcll(b0) + (u32)__popcll(b1 & mlt);
        u32 flat = (u32)p * NFG + (u32)(63 + lid);              // class-1 = 64+lid-1
        if ((int)pos < cap)
            cb[pos] = ((u64)__float_as_uint(sc1) << 32) | (u64)(0xFFFFFFFFu - flat);
    }
}

// ============================================================ kernel 2
// exact top-1000 per image: two-level float-bit histogram + bitonic sort
__device__ __forceinline__ void suffix_scan8192(u32* s, int tid) {
    for (int d = 1; d < 8192; d <<= 1) {
        u32 v[8];
        #pragma unroll
        for (int r = 0; r < 8; ++r) {
            int i = tid + r * 1024;
            v[r] = s[i] + ((i + d < 8192) ? s[i + d] : 0u);
        }
        __syncthreads();
        #pragma unroll
        for (int r = 0; r < 8; ++r) s[tid + r * 1024] = v[r];
        __syncthreads();
    }
}

__global__ __launch_bounds__(1024) void k_select(
    const u64* __restrict__ cand, const u32* __restrict__ cnt,
    u64* __restrict__ topk, int cap)
{
    __shared__ u32 hist[8192];
    __shared__ u64 buf[2048];
    __shared__ int sh_c, sh_nhi;
    __shared__ u32 sh_T, sh_m;
    int b = blockIdx.x, tid = threadIdx.x;
    const int nt = 1024;
    u32 n = min(cnt[b], (u32)cap);
    const u64* cb = cand + (size_t)b * cap;

    for (int i = tid; i < 8192; i += nt) hist[i] = 0;
    if (tid == 0) { sh_c = -2; sh_T = 0; sh_m = 0; sh_nhi = 0; }
    __syncthreads();
    for (u32 i = tid; i < n; i += nt) {
        u32 bits = (u32)(cb[i] >> 32);
        atomicAdd(&hist[(bits - BASEBITS) >> 13], 1u);
    }
    __syncthreads();
    suffix_scan8192(hist, tid);
    for (int i = tid; i < 8192; i += nt) {
        u32 si = hist[i], sn = (i + 1 < 8192) ? hist[i + 1] : 0u;
        if (si >= KTOP && sn < KTOP) { sh_c = i; sh_nhi = (int)sn; }
    }
    __syncthreads();
    int c = sh_c;
    u32 T = 0;
    if (c >= 0) {
        u32 nhi = (u32)sh_nhi;
        __syncthreads();
        for (int i = tid; i < 8192; i += nt) hist[i] = 0;
        __syncthreads();
        for (u32 i = tid; i < n; i += nt) {
            u32 bits = (u32)(cb[i] >> 32);
            if ((int)((bits - BASEBITS) >> 13) == c) atomicAdd(&hist[bits & 0x1FFFu], 1u);
        }
        __syncthreads();
        suffix_scan8192(hist, tid);
        for (int i = tid; i < 8192; i += nt) {
            u32 si = hist[i] + nhi;
            u32 sn = ((i + 1 < 8192) ? hist[i + 1] : 0u) + nhi;
            if (si >= KTOP && sn < KTOP)
                sh_T = BASEBITS + ((u32)c << 13) + (u32)i;
        }
        __syncthreads();
        T = sh_T;
    }
    // collect survivors (>= T), then pad + bitonic sort descending by full key
    for (u32 i = tid; i < n; i += nt) {
        u64 key = cb[i];
        if ((u32)(key >> 32) >= T) {
            u32 pos = atomicAdd(&sh_m, 1u);
            if (pos < 2048) buf[pos] = key;
        }
    }
    __syncthreads();
    u32 mm = min(sh_m, 2048u);
    for (int i = tid; i < 2048; i += nt) if ((u32)i >= mm) buf[i] = 0ULL;
    __syncthreads();
    for (int k = 2; k <= 2048; k <<= 1) {
        for (int j = k >> 1; j > 0; j >>= 1) {
            for (int i = tid; i < 2048; i += nt) {
                int ixj = i ^ j;
                if (ixj > i) {
                    u64 a = buf[i], bb = buf[ixj];
                    bool up = (i & k) == 0;
                    if (up ? (a < bb) : (a > bb)) { buf[i] = bb; buf[ixj] = a; }
                }
            }
            __syncthreads();
        }
    }
    for (int i = tid; i < KTOP; i += nt) topk[b * KPAD + i] = buf[i];
}

// ============================================================ kernel 3
// gather candidate boxes, max_coord reduce, class-offset boxes + areas
__global__ __launch_bounds__(1024) void k_prep(
    const u64* __restrict__ topk, const float* __restrict__ boxes,
    float* __restrict__ cscore, int* __restrict__ clabel,
    float4* __restrict__ cbox, float4* __restrict__ coffs,
    float* __restrict__ carea, u64* __restrict__ validw)
{
#pragma clang fp contract(off)
    __shared__ float red[1024];
    int b = blockIdx.x, i = threadIdx.x;
    u64 key = (i < KTOP) ? topk[b * KPAD + i] : 0ULL;
    float s = __uint_as_float((u32)(key >> 32));
    bool valid = s > 0.0f;
    u32 flat = valid ? (0xFFFFFFFFu - (u32)key) : 0u;
    int prior = (int)(flat / NFG);
    int cls = (int)(flat - (u32)prior * NFG) + 1;
    float4 bx = make_float4(0.f, 0.f, 0.f, 0.f);
    if (valid) bx = ((const float4*)boxes)[b * NP + prior];
    cscore[b * KPAD + i] = s;
    clabel[b * KPAD + i] = cls;
    cbox[b * KPAD + i] = bx;
    u64 vb = __ballot(valid);
    if ((i & 63) == 0) validw[b * 16 + (i >> 6)] = vb;
    float lm = valid ? fmaxf(fmaxf(bx.x, bx.y), fmaxf(bx.z, bx.w)) : 0.0f;
    red[i] = fmaxf(lm, 0.0f);
    __syncthreads();
    for (int d = 512; d > 0; d >>= 1) {
        if (i < d) red[i] = fmaxf(red[i], red[i + d]);
        __syncthreads();
    }
    float mc = red[0];
    float off = (float)cls * (mc + 1.0f);
    float4 ob = valid ? make_float4(bx.x + off, bx.y + off, bx.z + off, bx.w + off)
                      : make_float4(0.f, 0.f, 0.f, 0.f);
    float area = valid ? (ob.z - ob.x) * (ob.w - ob.y) : 0.0f;
    coffs[b * KPAD + i] = ob;
    carea[b * KPAD + i] = area;
}

// ============================================================ kernel 4
// suppression bitmask: lane-per-row, wave-uniform column loop (LDS broadcast)
__global__ __launch_bounds__(1024) void k_iou(
    const float4* __restrict__ coffs, const float* __restrict__ carea,
    u64* __restrict__ mask)
{
#pragma clang fp contract(off)
    __shared__ float4 bs[KPAD];
    __shared__ float as_[KPAD];
    int b = blockIdx.x >> 4, tile = blockIdx.x & 15;
    int t = threadIdx.x;
    bs[t] = coffs[b * KPAD + t];
    as_[t] = carea[b * KPAD + t];
    __syncthreads();
    int i = tile * 64 + (t & 63);
    int w = t >> 6;
    u64 bits = 0;
    if (i < KTOP) {
        float4 bi = bs[i];
        float ai = as_[i];
        int j0 = w * 64;
        #pragma unroll 4
        for (int jj = 0; jj < 64; ++jj) {
            int j = j0 + jj;
            float4 bj = bs[j];
            float aj = as_[j];
            float ltx = fmaxf(bi.x, bj.x), lty = fmaxf(bi.y, bj.y);
            float rbx = fminf(bi.z, bj.z), rby = fminf(bi.w, bj.w);
            float wx = fmaxf(rbx - ltx, 0.0f), wy = fmaxf(rby - lty, 0.0f);
            float inter = wx * wy;
            float denom = ((ai + aj) - inter) + 1e-9f;
            float iou = inter / denom;
            bool sup = (iou > 0.45f) && (j > i) && (j < KTOP);
            bits |= ((u64)sup) << jj;
        }
    }
    mask[((size_t)b * KPAD + i) * 16 + w] = bits;
}

// ============================================================ kernel 5
// serial greedy NMS scan (hierarchical, one wave per image) + emit top-100
__global__ __launch_bounds__(64) void k_nms(
    const u64* __restrict__ mask, const u64* __restrict__ validw,
    const float* __restrict__ cscore, const int* __restrict__ clabel,
    const float4* __restrict__ cbox, float* __restrict__ out)
{
    int b = blockIdx.x, lane = threadIdx.x;
    const u64* mk = mask + (size_t)b * KPAD * 16;
    u64 removed = 0;
    u64 vw = (lane < 16) ? validw[b * 16 + lane] : 0ULL;
    u64 keptw = 0;
    int w = lane & 15, kb = lane >> 4;
    for (int g = 0; g < 16; ++g) {
        int row = g * 64 + lane;
        u64 wself = (row < KTOP) ? mk[row * 16 + g] : 0ULL;
        u64 part[16];
        #pragma unroll
        for (int m = 0; m < 16; ++m) {              // issued before the serial chain
            int r2 = g * 64 + kb + (m << 2);
            part[m] = (r2 < KTOP) ? mk[r2 * 16 + w] : 0ULL;
        }
        u64 rg = __shfl(removed, g);
        u64 vg = __shfl(vw, g);
        u64 km = 0;
        for (int k = 0; k < 64; ++k) {
            u64 wk = __shfl(wself, k);
            bool keep = ((vg >> k) & 1ULL) && !((rg >> k) & 1ULL);
            if (keep) { rg |= wk; km |= 1ULL << k; }
        }
        u64 acc = 0;
        #pragma unroll
        for (int m = 0; m < 16; ++m) {
            int k = kb + (m << 2);
            if ((km >> k) & 1ULL) acc |= part[m];
        }
        acc |= __shfl_xor(acc, 16);
        acc |= __shfl_xor(acc, 32);
        if (lane < 16) removed |= acc;
        if (lane == g) { removed |= rg; keptw = km; }
    }
    __shared__ u64 sk[16];
    __shared__ int pfx[17];
    __shared__ int slot[DETS];
    if (lane < 16) sk[lane] = keptw & vw & ~removed;
    __syncthreads();
    if (lane == 0) {
        int run = 0;
        for (int l = 0; l < 16; ++l) { pfx[l] = run; run += __popcll(sk[l]); }
        pfx[16] = run;
    }
    __syncthreads();
    if (lane < 16) {
        int r = pfx[lane];
        u64 wv = sk[lane];
        while (wv && r < DETS) {
            int bit = __builtin_ctzll(wv);
            slot[r] = lane * 64 + bit;
            ++r;
            wv &= wv - 1;
        }
    }
    __syncthreads();
    int total = min(pfx[16], DETS);
    for (int r = lane; r < DETS; r += 64) {
        float4 bx = make_float4(0.f, 0.f, 0.f, 0.f);
        float s = 0.0f;
        int lb = -1;
        if (r < total) {
            int cdx = slot[r];
            bx = cbox[b * KPAD + cdx];
            s = cscore[b * KPAD + cdx];
            lb = clabel[b * KPAD + cdx];
        }
        float* ob = out + ((size_t)b * DETS + r) * 4;
        ob[0] = bx.x; ob[1] = bx.y; ob[2] = bx.z; ob[3] = bx.w;
        out[NIMG * DETS * 4 + b * DETS + r] = s;
        out[NIMG * DETS * 4 + NIMG * DETS + b * DETS + r] = (float)lb;
    }
}

// ============================================================ launch
extern "C" void kernel_launch(void* const* d_in, const int* in_sizes, int n_in,
                              void* d_out, int out_size, void* d_ws, size_t ws_size,
                              hipStream_t stream) {
    const float* logits = (const float*)d_in[0];
    const float* rel    = (const float*)d_in[1];
    const float* priors = (const float*)d_in[2];
    const int*   tsz    = (const int*)d_in[3];
    float* out = (float*)d_out;
    char* ws = (char*)d_ws;

    float* boxes  = (float*)(ws + OFF_BOXES);
    u32*   cnt    = (u32*)(ws + OFF_CNT);
    u64*   topk   = (u64*)(ws + OFF_TOPK);
    float* cscore = (float*)(ws + OFF_CSCORE);
    int*   clabel = (int*)(ws + OFF_CLABEL);
    float4* cbox  = (float4*)(ws + OFF_CBOX);
    float4* coffs = (float4*)(ws + OFF_COFFS);
    float* carea  = (float*)(ws + OFF_CAREA);
    u64*   validw = (u64*)(ws + OFF_VALIDW);
    u64*   mask   = (u64*)(ws + OFF_MASK);
    u64*   cand   = (u64*)(ws + OFF_CAND);

    // candidate capacity per image, bounded by workspace; 166912 >= hard max (19/prior)
    long long avail = ((long long)ws_size - (long long)OFF_CAND) / (NIMG * 8);
    int cap = (int)(avail < CAPMAX ? (avail > 0 ? avail : 1) : CAPMAX);

    hipMemsetAsync(cnt, 0, 64, stream);
    k_decode<<<(NIMG * NP) / 4, 256, 0, stream>>>(logits, rel, priors, tsz,
                                                  boxes, cand, cnt, cap);
    k_select<<<NIMG, 1024, 0, stream>>>(cand, cnt, topk, cap);
    k_prep<<<NIMG, 1024, 0, stream>>>(topk, boxes, cscore, clabel, cbox, coffs,
                                      carea, validw);
    k_iou<<<NIMG * 16, 1024, 0, stream>>>(coffs, carea, mask);
    k_nms<<<NIMG, 64, 0, stream>>>(mask, validw, cscore, clabel, cbox, out);
}

// Round 2
// 386.458 us; speedup vs baseline: 4.7343x; 4.7343x over previous
//
#include <hip/hip_runtime.h>
#include <math.h>

#pragma clang fp contract(off)

#define NIMG 16
#define NP   8732
#define NCLS 81
#define NFG  80
#define KTOP 1000
#define KPAD 1024
#define DETS 100
#define CAPMAX 166912          // >= 19*8732 (hard bound: <=19 softmax scores can exceed 0.05)
#define BASEBITS 0x3D000000u   // float bits of 0.03125, below 0.05 threshold; low 13 bits zero
#define CNT_STRIDE 64          // u32 units -> 256 B per image counter (own cacheline)

// ---- workspace layout (bytes) ----
#define OFF_BOXES  0u            // [NIMG][NP][4] f32  = 2,235,392
#define OFF_CNT    2235392u      // [NIMG] u32 padded to 256B each = 4096
#define OFF_TOPK   2239488u      // [NIMG][KPAD] u64   = 131,072
#define OFF_CSCORE 2370560u      // [NIMG][KPAD] f32
#define OFF_CLABEL 2436096u      // [NIMG][KPAD] i32
#define OFF_CBOX   2501632u      // [NIMG][KPAD] float4
#define OFF_COFFS  2763776u      // [NIMG][KPAD] float4
#define OFF_CAREA  3025920u      // [NIMG][KPAD] f32
#define OFF_VALIDW 3091456u      // [NIMG][16] u64
#define OFF_MASK   3093504u      // [NIMG][KPAD][16] u64 = 2,097,152
#define OFF_CAND   5190656u      // [NIMG][cap] u64

typedef unsigned long long u64;
typedef unsigned int u32;

// ============================================================ kernel 1
// one wave per prior: decode box, softmax over 81 classes, compact candidates.
// atomics: ONE per block (4 waves, same image), per-image counters padded to
// separate cachelines -- R1 showed per-wave atomics on one shared cacheline
// serialized the whole kernel (1590us at 3% VALUBusy).
__global__ __launch_bounds__(256) void k_decode(
    const float* __restrict__ logits, const float* __restrict__ rel,
    const float* __restrict__ priors, const int* __restrict__ tsz,
    float* __restrict__ boxes_out, u64* __restrict__ cand,
    u32* __restrict__ cnt, int cap)
{
#pragma clang fp contract(off)
    __shared__ u32 s_tot[4];
    int wv = threadIdx.x >> 6;
    int wave = blockIdx.x * 4 + wv;
    int lid  = threadIdx.x & 63;
    int b = wave / NP, p = wave - b * NP;   // 8732 % 4 == 0: whole block same image
    size_t lbase = (size_t)(b * NP + p) * NCLS;
    float x0 = logits[lbase + lid];
    float x1 = (lid < 17) ? logits[lbase + 64 + lid] : -3.4e38f;

    int size_ok = 0;
    if (lid == 0) {
        const float* pr = priors + (size_t)p * 4;
        const float* rl = rel + (size_t)(b * NP + p) * 4;
        float W = (float)tsz[b * 2 + 1], H = (float)tsz[b * 2 + 0];
        float cx = pr[0] + (rl[0] * 0.1f) * pr[2];
        float cy = pr[1] + (rl[1] * 0.1f) * pr[3];
        float w_ = pr[2] * expf(rl[2] * 0.2f);
        float h_ = pr[3] * expf(rl[3] * 0.2f);
        float sx1 = (cx - 0.5f * w_) * W, sy1 = (cy - 0.5f * h_) * H;
        float sx2 = (cx + 0.5f * w_) * W, sy2 = (cy + 0.5f * h_) * H;
        float4 bx = make_float4(sx1, sy1, sx2, sy2);
        ((float4*)boxes_out)[b * NP + p] = bx;
        size_ok = ((sx2 - sx1) >= 0.01f) && ((sy2 - sy1) >= 0.01f);
    }
    size_ok = __shfl(size_ok, 0);

    float m = fmaxf(x0, x1);
    for (int d = 1; d < 64; d <<= 1) m = fmaxf(m, __shfl_xor(m, d));
    float e0 = expf(x0 - m);
    float e1 = (lid < 17) ? expf(x1 - m) : 0.0f;
    float s = e0 + e1;
    for (int d = 1; d < 64; d <<= 1) s += __shfl_xor(s, d);
    float sc0 = e0 / s;
    float sc1 = e1 / s;

    bool v0 = (lid >= 1) && size_ok && (sc0 > 0.05f);           // classes 1..63
    bool v1 = (lid <= 16) && size_ok && (sc1 > 0.05f);          // classes 64..80
    u64 b0 = __ballot(v0), b1 = __ballot(v1);
    int tot = __popcll(b0) + __popcll(b1);

    if (lid == 0) s_tot[wv] = (u32)tot;
    __syncthreads();
    if (threadIdx.x == 0) {
        u32 t0 = s_tot[0], t1 = s_tot[1], t2 = s_tot[2], t3 = s_tot[3];
        u32 bt = t0 + t1 + t2 + t3;
        u32 base = bt ? atomicAdd(cnt + b * CNT_STRIDE, bt) : 0u;
        s_tot[0] = base;
        s_tot[1] = base + t0;
        s_tot[2] = base + t0 + t1;
        s_tot[3] = base + t0 + t1 + t2;
    }
    __syncthreads();
    u32 base = s_tot[wv];

    u64 mlt = (1ULL << lid) - 1ULL;
    u64* cb = cand + (size_t)b * cap;
    if (v0) {
        u32 pos = base + (u32)__popcll(b0 & mlt);
        u32 flat = (u32)p * NFG + (u32)(lid - 1);
        if ((int)pos < cap)
            cb[pos] = ((u64)__float_as_uint(sc0) << 32) | (u64)(0xFFFFFFFFu - flat);
    }
    if (v1) {
        u32 pos = base + (u32)__popcll(b0) + (u32)__popcll(b1 & mlt);
        u32 flat = (u32)p * NFG + (u32)(63 + lid);              // class-1 = 64+lid-1
        if ((int)pos < cap)
            cb[pos] = ((u64)__float_as_uint(sc1) << 32) | (u64)(0xFFFFFFFFu - flat);
    }
}

// ============================================================ kernel 2
// exact top-1000 per image: two-level float-bit histogram + bitonic sort
__device__ __forceinline__ void suffix_scan8192(u32* s, int tid) {
    for (int d = 1; d < 8192; d <<= 1) {
        u32 v[8];
        #pragma unroll
        for (int r = 0; r < 8; ++r) {
            int i = tid + r * 1024;
            v[r] = s[i] + ((i + d < 8192) ? s[i + d] : 0u);
        }
        __syncthreads();
        #pragma unroll
        for (int r = 0; r < 8; ++r) s[tid + r * 1024] = v[r];
        __syncthreads();
    }
}

__global__ __launch_bounds__(1024) void k_select(
    const u64* __restrict__ cand, const u32* __restrict__ cnt,
    u64* __restrict__ topk, int cap)
{
    __shared__ u32 hist[8192];
    __shared__ u64 buf[2048];
    __shared__ int sh_c, sh_nhi;
    __shared__ u32 sh_T, sh_m;
    int b = blockIdx.x, tid = threadIdx.x;
    const int nt = 1024;
    u32 n = min(cnt[b * CNT_STRIDE], (u32)cap);
    const u64* cb = cand + (size_t)b * cap;

    for (int i = tid; i < 8192; i += nt) hist[i] = 0;
    if (tid == 0) { sh_c = -2; sh_T = 0; sh_m = 0; sh_nhi = 0; }
    __syncthreads();
    for (u32 i = tid; i < n; i += nt) {
        u32 bits = (u32)(cb[i] >> 32);
        atomicAdd(&hist[(bits - BASEBITS) >> 13], 1u);
    }
    __syncthreads();
    suffix_scan8192(hist, tid);
    for (int i = tid; i < 8192; i += nt) {
        u32 si = hist[i], sn = (i + 1 < 8192) ? hist[i + 1] : 0u;
        if (si >= KTOP && sn < KTOP) { sh_c = i; sh_nhi = (int)sn; }
    }
    __syncthreads();
    int c = sh_c;
    u32 T = 0;
    if (c >= 0) {
        u32 nhi = (u32)sh_nhi;
        __syncthreads();
        for (int i = tid; i < 8192; i += nt) hist[i] = 0;
        __syncthreads();
        for (u32 i = tid; i < n; i += nt) {
            u32 bits = (u32)(cb[i] >> 32);
            if ((int)((bits - BASEBITS) >> 13) == c) atomicAdd(&hist[bits & 0x1FFFu], 1u);
        }
        __syncthreads();
        suffix_scan8192(hist, tid);
        for (int i = tid; i < 8192; i += nt) {
            u32 si = hist[i] + nhi;
            u32 sn = ((i + 1 < 8192) ? hist[i + 1] : 0u) + nhi;
            if (si >= KTOP && sn < KTOP)
                sh_T = BASEBITS + ((u32)c << 13) + (u32)i;
        }
        __syncthreads();
        T = sh_T;
    }
    // collect survivors (>= T), then pad + bitonic sort descending by full key
    for (u32 i = tid; i < n; i += nt) {
        u64 key = cb[i];
        if ((u32)(key >> 32) >= T) {
            u32 pos = atomicAdd(&sh_m, 1u);
            if (pos < 2048) buf[pos] = key;
        }
    }
    __syncthreads();
    u32 mm = min(sh_m, 2048u);
    for (int i = tid; i < 2048; i += nt) if ((u32)i >= mm) buf[i] = 0ULL;
    __syncthreads();
    for (int k = 2; k <= 2048; k <<= 1) {
        for (int j = k >> 1; j > 0; j >>= 1) {
            for (int i = tid; i < 2048; i += nt) {
                int ixj = i ^ j;
                if (ixj > i) {
                    u64 a = buf[i], bb = buf[ixj];
                    bool up = (i & k) == 0;
                    if (up ? (a < bb) : (a > bb)) { buf[i] = bb; buf[ixj] = a; }
                }
            }
            __syncthreads();
        }
    }
    for (int i = tid; i < KTOP; i += nt) topk[b * KPAD + i] = buf[i];
}

// ============================================================ kernel 3
// gather candidate boxes, max_coord reduce, class-offset boxes + areas
__global__ __launch_bounds__(1024) void k_prep(
    const u64* __restrict__ topk, const float* __restrict__ boxes,
    float* __restrict__ cscore, int* __restrict__ clabel,
    float4* __restrict__ cbox, float4* __restrict__ coffs,
    float* __restrict__ carea, u64* __restrict__ validw)
{
#pragma clang fp contract(off)
    __shared__ float red[1024];
    int b = blockIdx.x, i = threadIdx.x;
    u64 key = (i < KTOP) ? topk[b * KPAD + i] : 0ULL;
    float s = __uint_as_float((u32)(key >> 32));
    bool valid = s > 0.0f;
    u32 flat = valid ? (0xFFFFFFFFu - (u32)key) : 0u;
    int prior = (int)(flat / NFG);
    int cls = (int)(flat - (u32)prior * NFG) + 1;
    float4 bx = make_float4(0.f, 0.f, 0.f, 0.f);
    if (valid) bx = ((const float4*)boxes)[b * NP + prior];
    cscore[b * KPAD + i] = s;
    clabel[b * KPAD + i] = cls;
    cbox[b * KPAD + i] = bx;
    u64 vb = __ballot(valid);
    if ((i & 63) == 0) validw[b * 16 + (i >> 6)] = vb;
    float lm = valid ? fmaxf(fmaxf(bx.x, bx.y), fmaxf(bx.z, bx.w)) : 0.0f;
    red[i] = fmaxf(lm, 0.0f);
    __syncthreads();
    for (int d = 512; d > 0; d >>= 1) {
        if (i < d) red[i] = fmaxf(red[i], red[i + d]);
        __syncthreads();
    }
    float mc = red[0];
    float off = (float)cls * (mc + 1.0f);
    float4 ob = valid ? make_float4(bx.x + off, bx.y + off, bx.z + off, bx.w + off)
                      : make_float4(0.f, 0.f, 0.f, 0.f);
    float area = valid ? (ob.z - ob.x) * (ob.w - ob.y) : 0.0f;
    coffs[b * KPAD + i] = ob;
    carea[b * KPAD + i] = area;
}

// ============================================================ kernel 4
// suppression bitmask: lane-per-row, wave-uniform column loop (LDS broadcast)
__global__ __launch_bounds__(1024) void k_iou(
    const float4* __restrict__ coffs, const float* __restrict__ carea,
    u64* __restrict__ mask)
{
#pragma clang fp contract(off)
    __shared__ float4 bs[KPAD];
    __shared__ float as_[KPAD];
    int b = blockIdx.x >> 4, tile = blockIdx.x & 15;
    int t = threadIdx.x;
    bs[t] = coffs[b * KPAD + t];
    as_[t] = carea[b * KPAD + t];
    __syncthreads();
    int i = tile * 64 + (t & 63);
    int w = t >> 6;
    u64 bits = 0;
    if (i < KTOP) {
        float4 bi = bs[i];
        float ai = as_[i];
        int j0 = w * 64;
        #pragma unroll 4
        for (int jj = 0; jj < 64; ++jj) {
            int j = j0 + jj;
            float4 bj = bs[j];
            float aj = as_[j];
            float ltx = fmaxf(bi.x, bj.x), lty = fmaxf(bi.y, bj.y);
            float rbx = fminf(bi.z, bj.z), rby = fminf(bi.w, bj.w);
            float wx = fmaxf(rbx - ltx, 0.0f), wy = fmaxf(rby - lty, 0.0f);
            float inter = wx * wy;
            float denom = ((ai + aj) - inter) + 1e-9f;
            float iou = inter / denom;
            bool sup = (iou > 0.45f) && (j > i) && (j < KTOP);
            bits |= ((u64)sup) << jj;
        }
    }
    mask[((size_t)b * KPAD + i) * 16 + w] = bits;
}

// ============================================================ kernel 5
// serial greedy NMS scan (hierarchical, one wave per image) + emit top-100
__global__ __launch_bounds__(64) void k_nms(
    const u64* __restrict__ mask, const u64* __restrict__ validw,
    const float* __restrict__ cscore, const int* __restrict__ clabel,
    const float4* __restrict__ cbox, float* __restrict__ out)
{
    int b = blockIdx.x, lane = threadIdx.x;
    const u64* mk = mask + (size_t)b * KPAD * 16;
    u64 removed = 0;
    u64 vw = (lane < 16) ? validw[b * 16 + lane] : 0ULL;
    u64 keptw = 0;
    int w = lane & 15, kb = lane >> 4;
    for (int g = 0; g < 16; ++g) {
        int row = g * 64 + lane;
        u64 wself = (row < KTOP) ? mk[row * 16 + g] : 0ULL;
        u64 part[16];
        #pragma unroll
        for (int m = 0; m < 16; ++m) {              // issued before the serial chain
            int r2 = g * 64 + kb + (m << 2);
            part[m] = (r2 < KTOP) ? mk[r2 * 16 + w] : 0ULL;
        }
        u64 rg = __shfl(removed, g);
        u64 vg = __shfl(vw, g);
        u64 km = 0;
        for (int k = 0; k < 64; ++k) {
            u64 wk = __shfl(wself, k);
            bool keep = ((vg >> k) & 1ULL) && !((rg >> k) & 1ULL);
            if (keep) { rg |= wk; km |= 1ULL << k; }
        }
        u64 acc = 0;
        #pragma unroll
        for (int m = 0; m < 16; ++m) {
            int k = kb + (m << 2);
            if ((km >> k) & 1ULL) acc |= part[m];
        }
        acc |= __shfl_xor(acc, 16);
        acc |= __shfl_xor(acc, 32);
        if (lane < 16) removed |= acc;
        if (lane == g) { removed |= rg; keptw = km; }
    }
    __shared__ u64 sk[16];
    __shared__ int pfx[17];
    __shared__ int slot[DETS];
    if (lane < 16) sk[lane] = keptw & vw & ~removed;
    __syncthreads();
    if (lane == 0) {
        int run = 0;
        for (int l = 0; l < 16; ++l) { pfx[l] = run; run += __popcll(sk[l]); }
        pfx[16] = run;
    }
    __syncthreads();
    if (lane < 16) {
        int r = pfx[lane];
        u64 wv = sk[lane];
        while (wv && r < DETS) {
            int bit = __builtin_ctzll(wv);
            slot[r] = lane * 64 + bit;
            ++r;
            wv &= wv - 1;
        }
    }
    __syncthreads();
    int total = min(pfx[16], DETS);
    for (int r = lane; r < DETS; r += 64) {
        float4 bx = make_float4(0.f, 0.f, 0.f, 0.f);
        float s = 0.0f;
        int lb = -1;
        if (r < total) {
            int cdx = slot[r];
            bx = cbox[b * KPAD + cdx];
            s = cscore[b * KPAD + cdx];
            lb = clabel[b * KPAD + cdx];
        }
        float* ob = out + ((size_t)b * DETS + r) * 4;
        ob[0] = bx.x; ob[1] = bx.y; ob[2] = bx.z; ob[3] = bx.w;
        out[NIMG * DETS * 4 + b * DETS + r] = s;
        out[NIMG * DETS * 4 + NIMG * DETS + b * DETS + r] = (float)lb;
    }
}

// ============================================================ launch
extern "C" void kernel_launch(void* const* d_in, const int* in_sizes, int n_in,
                              void* d_out, int out_size, void* d_ws, size_t ws_size,
                              hipStream_t stream) {
    const float* logits = (const float*)d_in[0];
    const float* rel    = (const float*)d_in[1];
    const float* priors = (const float*)d_in[2];
    const int*   tsz    = (const int*)d_in[3];
    float* out = (float*)d_out;
    char* ws = (char*)d_ws;

    float* boxes  = (float*)(ws + OFF_BOXES);
    u32*   cnt    = (u32*)(ws + OFF_CNT);
    u64*   topk   = (u64*)(ws + OFF_TOPK);
    float* cscore = (float*)(ws + OFF_CSCORE);
    int*   clabel = (int*)(ws + OFF_CLABEL);
    float4* cbox  = (float4*)(ws + OFF_CBOX);
    float4* coffs = (float4*)(ws + OFF_COFFS);
    float* carea  = (float*)(ws + OFF_CAREA);
    u64*   validw = (u64*)(ws + OFF_VALIDW);
    u64*   mask   = (u64*)(ws + OFF_MASK);
    u64*   cand   = (u64*)(ws + OFF_CAND);

    // candidate capacity per image, bounded by workspace; 166912 >= hard max (19/prior)
    long long avail = ((long long)ws_size - (long long)OFF_CAND) / (NIMG * 8);
    int cap = (int)(avail < CAPMAX ? (avail > 0 ? avail : 1) : CAPMAX);

    hipMemsetAsync(cnt, 0, NIMG * CNT_STRIDE * 4, stream);
    k_decode<<<(NIMG * NP) / 4, 256, 0, stream>>>(logits, rel, priors, tsz,
                                                  boxes, cand, cnt, cap);
    k_select<<<NIMG, 1024, 0, stream>>>(cand, cnt, topk, cap);
    k_prep<<<NIMG, 1024, 0, stream>>>(topk, boxes, cscore, clabel, cbox, coffs,
                                      carea, validw);
    k_iou<<<NIMG * 16, 1024, 0, stream>>>(coffs, carea, mask);
    k_nms<<<NIMG, 64, 0, stream>>>(mask, validw, cscore, clabel, cbox, out);
}

// Round 3
// 292.768 us; speedup vs baseline: 6.2493x; 1.3200x over previous
//
#include <hip/hip_runtime.h>
#include <math.h>

#pragma clang fp contract(off)

#define NIMG 16
#define NP   8732
#define NCLS 81
#define NFG  80
#define KTOP 1000
#define KPAD 1024
#define DETS 100
#define CAPMAX 166912          // >= 19*8732 (hard bound: <=19 softmax scores can exceed 0.05)
#define BASEBITS 0x3D000000u   // float bits of 0.03125, below 0.05 threshold; low 13 bits zero
#define CNT_STRIDE 64          // u32 units -> 256 B per image counter (own cacheline)
#define TILEB 137              // blocks per image in k_decode (137*64 >= 8732)
#define LROW 65                // padded LDS row stride (floats): bank = (c+p)%32, conflict-free

// ---- workspace layout (bytes) ----
#define OFF_BOXES  0u            // [NIMG][NP][4] f32  = 2,235,392
#define OFF_CNT    2235392u      // [NIMG] u32 padded to 256B each = 4096
#define OFF_TOPK   2239488u      // [NIMG][KPAD] u64   = 131,072
#define OFF_CSCORE 2370560u      // [NIMG][KPAD] f32
#define OFF_CLABEL 2436096u      // [NIMG][KPAD] i32
#define OFF_CBOX   2501632u      // [NIMG][KPAD] float4
#define OFF_COFFS  2763776u      // [NIMG][KPAD] float4
#define OFF_CAREA  3025920u      // [NIMG][KPAD] f32
#define OFF_VALIDW 3091456u      // [NIMG][16] u64
#define OFF_MASK   3093504u      // [NIMG][KPAD][16] u64 = 2,097,152
#define OFF_CAND   5190656u      // [NIMG][cap] u64

typedef unsigned long long u64;
typedef unsigned int u32;

// ============================================================ kernel 1
// thread-per-prior, LDS-transposed staging. R2's wave-per-prior version sat at
// 2.4% HBM / 26% VALU: 12-deep ds_swizzle chains + block sync + divergent
// decode dominated. Here: coalesced global->LDS (transposed, stride 65 =>
// conflict-free), per-thread register softmax, one atomic per wave.
__global__ __launch_bounds__(64, 2) void k_decode(
    const float* __restrict__ logits, const float* __restrict__ rel,
    const float* __restrict__ priors, const int* __restrict__ tsz,
    float* __restrict__ boxes_out, u64* __restrict__ cand,
    u32* __restrict__ cnt, int cap)
{
#pragma clang fp contract(off)
    __shared__ float lx[NCLS * LROW];            // 21,060 B
    int b  = blockIdx.x / TILEB;
    int g  = blockIdx.x - b * TILEB;
    int p0 = g * 64;
    int t  = threadIdx.x;                         // lane == tid (single wave)

    // ---- phase A: coalesced global -> LDS, transposed to [class][prior] ----
    const float* src = logits + ((size_t)b * NP + p0) * NCLS;
    int limit = (NP - p0) * NCLS;
    if (limit > 64 * NCLS) limit = 64 * NCLS;     // tail tile: (NP-p0)*81, mult of 4
    {
        int c = t, p = 0;                          // fi = t: p=0, c=t (t<81)
        int addr = c * LROW;                       // + p (0)
        for (int fi = t; fi < limit; fi += 64) {
            lx[addr] = src[fi];
            c += 64; addr += 64 * LROW;
            if (c >= NCLS) { c -= NCLS; ++p; addr -= NCLS * LROW - 1; }
        }
    }
    __syncthreads();

    int p = p0 + t;
    bool active = p < NP;

    // ---- box decode (per-thread, coalesced float4) ----
    int size_ok = 0;
    if (active) {
        float4 pr = ((const float4*)priors)[p];
        float4 rl = ((const float4*)rel)[(size_t)b * NP + p];
        float W = (float)tsz[b * 2 + 1], H = (float)tsz[b * 2 + 0];
        float cx = pr.x + (rl.x * 0.1f) * pr.z;
        float cy = pr.y + (rl.y * 0.1f) * pr.w;
        float w_ = pr.z * expf(rl.z * 0.2f);
        float h_ = pr.w * expf(rl.w * 0.2f);
        float4 bx;
        bx.x = (cx - 0.5f * w_) * W; bx.y = (cy - 0.5f * h_) * H;
        bx.z = (cx + 0.5f * w_) * W; bx.w = (cy + 0.5f * h_) * H;
        ((float4*)boxes_out)[(size_t)b * NP + p] = bx;
        size_ok = ((bx.z - bx.x) >= 0.01f) && ((bx.w - bx.y) >= 0.01f);
    }

    // ---- own column -> registers ----
    float x[NCLS];
    #pragma unroll
    for (int c = 0; c < NCLS; ++c) x[c] = lx[c * LROW + t];

    // max (exact regardless of order), 4-wide ILP
    float m0 = x[0], m1 = x[1], m2 = x[2], m3 = x[3];
    #pragma unroll
    for (int c = 4; c + 3 < NCLS; c += 4) {
        m0 = fmaxf(m0, x[c]);     m1 = fmaxf(m1, x[c + 1]);
        m2 = fmaxf(m2, x[c + 2]); m3 = fmaxf(m3, x[c + 3]);
    }
    m0 = fmaxf(m0, x[80]);
    float m = fmaxf(fmaxf(m0, m1), fmaxf(m2, m3));

    // exp + sum (4 accumulators; e values bit-identical to ref's expf(x-m))
    float s0 = 0.f, s1 = 0.f, s2 = 0.f, s3 = 0.f;
    #pragma unroll
    for (int c = 0; c + 3 < NCLS; c += 4) {
        x[c]     = expf(x[c]     - m); s0 += x[c];
        x[c + 1] = expf(x[c + 1] - m); s1 += x[c + 1];
        x[c + 2] = expf(x[c + 2] - m); s2 += x[c + 2];
        x[c + 3] = expf(x[c + 3] - m); s3 += x[c + 3];
    }
    x[80] = expf(x[80] - m); s0 += x[80];
    float s = (s0 + s1) + (s2 + s3);

    // threshold: conservative band, exact f32-div fallback only inside band.
    // e > hi  => RN(e/s) > 0.05f guaranteed; e <= lo => RN(e/s) <= 0.05f.
    float hi = 0.05000075f * s;
    float lo = 0.04999925f * s;
    u64 bits_lo = 0, band_lo = 0;
    u32 bits_hi = 0, band_hi = 0;
    if (active && size_ok) {
        #pragma unroll
        for (int c = 1; c < NCLS; ++c) {
            float e = x[c];
            bool pass = e > hi;
            bool band = (!pass) && (e > lo);
            int cm1 = c - 1;
            if (cm1 < 64) {
                bits_lo |= ((u64)pass) << cm1;
                band_lo |= ((u64)band) << cm1;
            } else {
                bits_hi |= ((u32)pass) << (cm1 - 64);
                band_hi |= ((u32)band) << (cm1 - 64);
            }
        }
    }
    // resolve ambiguous band exactly (rare: ~few lanes per dispatch)
    while (band_lo) {
        int cm1 = __builtin_ctzll(band_lo); band_lo &= band_lo - 1;
        float e = expf(lx[(cm1 + 1) * LROW + t] - m);
        if (e / s > 0.05f) bits_lo |= 1ULL << cm1;
    }
    while (band_hi) {
        int j = __builtin_ctz(band_hi); band_hi &= band_hi - 1;
        float e = expf(lx[(j + 65) * LROW + t] - m);
        if (e / s > 0.05f) bits_hi |= 1u << j;
    }
    int cnt_t = __popcll(bits_lo) + __popc(bits_hi);

    // wave prefix sum + one atomic per wave
    int pre = cnt_t;
    #pragma unroll
    for (int d = 1; d < 64; d <<= 1) {
        int o = __shfl_up(pre, d);
        if (t >= d) pre += o;
    }
    u32 wbase = 0;
    if (t == 63) wbase = (pre > 0) ? atomicAdd(cnt + b * CNT_STRIDE, (u32)pre) : 0u;
    wbase = (u32)__shfl((int)wbase, 63);
    u32 pos = wbase + (u32)(pre - cnt_t);

    // emit: exact f32 div per passing class (avg ~3.6/thread)
    u64* cb = cand + (size_t)b * cap;
    u32 flatneg = 0xFFFFFFFFu - (u32)p * NFG;     // key low = flatneg - (c-1)
    while (bits_lo) {
        int cm1 = __builtin_ctzll(bits_lo); bits_lo &= bits_lo - 1;
        float e = expf(lx[(cm1 + 1) * LROW + t] - m);
        float d = e / s;
        if ((int)pos < cap)
            cb[pos] = ((u64)__float_as_uint(d) << 32) | (u64)(flatneg - (u32)cm1);
        ++pos;
    }
    while (bits_hi) {
        int j = __builtin_ctz(bits_hi); bits_hi &= bits_hi - 1;
        int cm1 = j + 64;
        float e = expf(lx[(cm1 + 1) * LROW + t] - m);
        float d = e / s;
        if ((int)pos < cap)
            cb[pos] = ((u64)__float_as_uint(d) << 32) | (u64)(flatneg - (u32)cm1);
        ++pos;
    }
}

// ============================================================ kernel 2
// exact top-1000 per image: two-level float-bit histogram + bitonic sort.
// suffix scan: 1-pass hierarchical (8 bins/thread -> wave shfl -> 16 totals)
// instead of 13-pass Hillis-Steele (R2).
__device__ __forceinline__ void suffix_find(
    u32* hist, u32* wt, u32 K, int tid,
    volatile int* outI, volatile u32* outNext)
{
    int lane = tid & 63, w = tid >> 6;
    u32 v[8]; u32 tot = 0;
    #pragma unroll
    for (int k = 0; k < 8; ++k) { v[k] = hist[tid * 8 + k]; tot += v[k]; }
    u32 ws = tot;
    #pragma unroll
    for (int d = 1; d < 64; d <<= 1) {
        u32 o = __shfl_down(ws, d);
        if (lane + d < 64) ws += o;
    }
    if (lane == 0) wt[w] = ws;                    // wave total
    __syncthreads();
    u32 tail = 0;
    for (int w2 = w + 1; w2 < 16; ++w2) tail += wt[w2];
    u32 after = (ws - tot) + tail;                // suffix strictly after my bins
    u32 sufk[9];
    sufk[8] = after;
    #pragma unroll
    for (int k = 7; k >= 0; --k) sufk[k] = v[k] + sufk[k + 1];
    #pragma unroll
    for (int k = 0; k < 8; ++k) {
        if (sufk[k] >= K && sufk[k + 1] < K) {    // unique boundary
            *outI = tid * 8 + k;
            *outNext = sufk[k + 1];
        }
    }
    __syncthreads();
}

__global__ __launch_bounds__(1024) void k_select(
    const u64* __restrict__ cand, const u32* __restrict__ cnt,
    u64* __restrict__ topk, int cap)
{
    __shared__ u32 hist[8192];
    __shared__ u64 buf[2048];
    __shared__ u32 wt[16];
    __shared__ int sh_c, sh_i2;
    __shared__ u32 sh_nhi, sh_m, sh_dummy;
    int b = blockIdx.x, tid = threadIdx.x;
    const int nt = 1024;
    u32 n = min(cnt[b * CNT_STRIDE], (u32)cap);
    const u64* cb = cand + (size_t)b * cap;

    for (int i = tid; i < 8192; i += nt) hist[i] = 0;
    if (tid == 0) { sh_c = -2; sh_i2 = -2; sh_nhi = 0; sh_m = 0; }
    __syncthreads();
    for (u32 i = tid; i < n; i += nt) {
        u32 bits = (u32)(cb[i] >> 32);
        atomicAdd(&hist[(bits - BASEBITS) >> 13], 1u);
    }
    __syncthreads();
    suffix_find(hist, wt, (u32)KTOP, tid, &sh_c, &sh_nhi);
    int c = sh_c;
    u32 T = 0;
    if (c >= 0) {
        u32 nhi = sh_nhi;                          // < KTOP by construction
        __syncthreads();
        for (int i = tid; i < 8192; i += nt) hist[i] = 0;
        __syncthreads();
        for (u32 i = tid; i < n; i += nt) {
            u32 bits = (u32)(cb[i] >> 32);
            if ((int)((bits - BASEBITS) >> 13) == c) atomicAdd(&hist[bits & 0x1FFFu], 1u);
        }
        __syncthreads();
        suffix_find(hist, wt, (u32)KTOP - nhi, tid, &sh_i2, &sh_dummy);
        T = (sh_i2 >= 0) ? (BASEBITS + ((u32)c << 13) + (u32)sh_i2) : 0u;
    }
    // collect survivors (>= T), then pad + bitonic sort descending by full key
    for (u32 i = tid; i < n; i += nt) {
        u64 key = cb[i];
        if ((u32)(key >> 32) >= T) {
            u32 pos = atomicAdd(&sh_m, 1u);
            if (pos < 2048) buf[pos] = key;
        }
    }
    __syncthreads();
    u32 mm = min(sh_m, 2048u);
    for (int i = tid; i < 2048; i += nt) if ((u32)i >= mm) buf[i] = 0ULL;
    __syncthreads();
    for (int k = 2; k <= 2048; k <<= 1) {
        for (int j = k >> 1; j > 0; j >>= 1) {
            for (int i = tid; i < 2048; i += nt) {
                int ixj = i ^ j;
                if (ixj > i) {
                    u64 a = buf[i], bb = buf[ixj];
                    bool up = (i & k) == 0;
                    if (up ? (a < bb) : (a > bb)) { buf[i] = bb; buf[ixj] = a; }
                }
            }
            __syncthreads();
        }
    }
    for (int i = tid; i < KTOP; i += nt) topk[b * KPAD + i] = buf[i];
}

// ============================================================ kernel 3
// gather candidate boxes, max_coord reduce, class-offset boxes + areas
__global__ __launch_bounds__(1024) void k_prep(
    const u64* __restrict__ topk, const float* __restrict__ boxes,
    float* __restrict__ cscore, int* __restrict__ clabel,
    float4* __restrict__ cbox, float4* __restrict__ coffs,
    float* __restrict__ carea, u64* __restrict__ validw)
{
#pragma clang fp contract(off)
    __shared__ float red[1024];
    int b = blockIdx.x, i = threadIdx.x;
    u64 key = (i < KTOP) ? topk[b * KPAD + i] : 0ULL;
    float s = __uint_as_float((u32)(key >> 32));
    bool valid = s > 0.0f;
    u32 flat = valid ? (0xFFFFFFFFu - (u32)key) : 0u;
    int prior = (int)(flat / NFG);
    int cls = (int)(flat - (u32)prior * NFG) + 1;
    float4 bx = make_float4(0.f, 0.f, 0.f, 0.f);
    if (valid) bx = ((const float4*)boxes)[b * NP + prior];
    cscore[b * KPAD + i] = s;
    clabel[b * KPAD + i] = cls;
    cbox[b * KPAD + i] = bx;
    u64 vb = __ballot(valid);
    if ((i & 63) == 0) validw[b * 16 + (i >> 6)] = vb;
    float lm = valid ? fmaxf(fmaxf(bx.x, bx.y), fmaxf(bx.z, bx.w)) : 0.0f;
    red[i] = fmaxf(lm, 0.0f);
    __syncthreads();
    for (int d = 512; d > 0; d >>= 1) {
        if (i < d) red[i] = fmaxf(red[i], red[i + d]);
        __syncthreads();
    }
    float mc = red[0];
    float off = (float)cls * (mc + 1.0f);
    float4 ob = valid ? make_float4(bx.x + off, bx.y + off, bx.z + off, bx.w + off)
                      : make_float4(0.f, 0.f, 0.f, 0.f);
    float area = valid ? (ob.z - ob.x) * (ob.w - ob.y) : 0.0f;
    coffs[b * KPAD + i] = ob;
    carea[b * KPAD + i] = area;
}

// ============================================================ kernel 4
// suppression bitmask: lane-per-row, wave-uniform column loop (LDS broadcast)
__global__ __launch_bounds__(1024) void k_iou(
    const float4* __restrict__ coffs, const float* __restrict__ carea,
    u64* __restrict__ mask)
{
#pragma clang fp contract(off)
    __shared__ float4 bs[KPAD];
    __shared__ float as_[KPAD];
    int b = blockIdx.x >> 4, tile = blockIdx.x & 15;
    int t = threadIdx.x;
    bs[t] = coffs[b * KPAD + t];
    as_[t] = carea[b * KPAD + t];
    __syncthreads();
    int i = tile * 64 + (t & 63);
    int w = t >> 6;
    u64 bits = 0;
    if (i < KTOP) {
        float4 bi = bs[i];
        float ai = as_[i];
        int j0 = w * 64;
        #pragma unroll 4
        for (int jj = 0; jj < 64; ++jj) {
            int j = j0 + jj;
            float4 bj = bs[j];
            float aj = as_[j];
            float ltx = fmaxf(bi.x, bj.x), lty = fmaxf(bi.y, bj.y);
            float rbx = fminf(bi.z, bj.z), rby = fminf(bi.w, bj.w);
            float wx = fmaxf(rbx - ltx, 0.0f), wy = fmaxf(rby - lty, 0.0f);
            float inter = wx * wy;
            float denom = ((ai + aj) - inter) + 1e-9f;
            float iou = inter / denom;
            bool sup = (iou > 0.45f) && (j > i) && (j < KTOP);
            bits |= ((u64)sup) << jj;
        }
    }
    mask[((size_t)b * KPAD + i) * 16 + w] = bits;
}

// ============================================================ kernel 5
// serial greedy NMS scan (hierarchical, one wave per image) + emit top-100
__global__ __launch_bounds__(64) void k_nms(
    const u64* __restrict__ mask, const u64* __restrict__ validw,
    const float* __restrict__ cscore, const int* __restrict__ clabel,
    const float4* __restrict__ cbox, float* __restrict__ out)
{
    int b = blockIdx.x, lane = threadIdx.x;
    const u64* mk = mask + (size_t)b * KPAD * 16;
    u64 removed = 0;
    u64 vw = (lane < 16) ? validw[b * 16 + lane] : 0ULL;
    u64 keptw = 0;
    int w = lane & 15, kb = lane >> 4;
    for (int g = 0; g < 16; ++g) {
        int row = g * 64 + lane;
        u64 wself = (row < KTOP) ? mk[row * 16 + g] : 0ULL;
        u64 part[16];
        #pragma unroll
        for (int m = 0; m < 16; ++m) {              // issued before the serial chain
            int r2 = g * 64 + kb + (m << 2);
            part[m] = (r2 < KTOP) ? mk[r2 * 16 + w] : 0ULL;
        }
        u64 rg = __shfl(removed, g);
        u64 vg = __shfl(vw, g);
        u64 km = 0;
        for (int k = 0; k < 64; ++k) {
            u64 wk = __shfl(wself, k);
            bool keep = ((vg >> k) & 1ULL) && !((rg >> k) & 1ULL);
            if (keep) { rg |= wk; km |= 1ULL << k; }
        }
        u64 acc = 0;
        #pragma unroll
        for (int m = 0; m < 16; ++m) {
            int k = kb + (m << 2);
            if ((km >> k) & 1ULL) acc |= part[m];
        }
        acc |= __shfl_xor(acc, 16);
        acc |= __shfl_xor(acc, 32);
        if (lane < 16) removed |= acc;
        if (lane == g) { removed |= rg; keptw = km; }
    }
    __shared__ u64 sk[16];
    __shared__ int pfx[17];
    __shared__ int slot[DETS];
    if (lane < 16) sk[lane] = keptw & vw & ~removed;
    __syncthreads();
    if (lane == 0) {
        int run = 0;
        for (int l = 0; l < 16; ++l) { pfx[l] = run; run += __popcll(sk[l]); }
        pfx[16] = run;
    }
    __syncthreads();
    if (lane < 16) {
        int r = pfx[lane];
        u64 wv = sk[lane];
        while (wv && r < DETS) {
            int bit = __builtin_ctzll(wv);
            slot[r] = lane * 64 + bit;
            ++r;
            wv &= wv - 1;
        }
    }
    __syncthreads();
    int total = min(pfx[16], DETS);
    for (int r = lane; r < DETS; r += 64) {
        float4 bx = make_float4(0.f, 0.f, 0.f, 0.f);
        float s = 0.0f;
        int lb = -1;
        if (r < total) {
            int cdx = slot[r];
            bx = cbox[b * KPAD + cdx];
            s = cscore[b * KPAD + cdx];
            lb = clabel[b * KPAD + cdx];
        }
        float* ob = out + ((size_t)b * DETS + r) * 4;
        ob[0] = bx.x; ob[1] = bx.y; ob[2] = bx.z; ob[3] = bx.w;
        out[NIMG * DETS * 4 + b * DETS + r] = s;
        out[NIMG * DETS * 4 + NIMG * DETS + b * DETS + r] = (float)lb;
    }
}

// ============================================================ launch
extern "C" void kernel_launch(void* const* d_in, const int* in_sizes, int n_in,
                              void* d_out, int out_size, void* d_ws, size_t ws_size,
                              hipStream_t stream) {
    const float* logits = (const float*)d_in[0];
    const float* rel    = (const float*)d_in[1];
    const float* priors = (const float*)d_in[2];
    const int*   tsz    = (const int*)d_in[3];
    float* out = (float*)d_out;
    char* ws = (char*)d_ws;

    float* boxes  = (float*)(ws + OFF_BOXES);
    u32*   cnt    = (u32*)(ws + OFF_CNT);
    u64*   topk   = (u64*)(ws + OFF_TOPK);
    float* cscore = (float*)(ws + OFF_CSCORE);
    int*   clabel = (int*)(ws + OFF_CLABEL);
    float4* cbox  = (float4*)(ws + OFF_CBOX);
    float4* coffs = (float4*)(ws + OFF_COFFS);
    float* carea  = (float*)(ws + OFF_CAREA);
    u64*   validw = (u64*)(ws + OFF_VALIDW);
    u64*   mask   = (u64*)(ws + OFF_MASK);
    u64*   cand   = (u64*)(ws + OFF_CAND);

    // candidate capacity per image, bounded by workspace; 166912 >= hard max (19/prior)
    long long avail = ((long long)ws_size - (long long)OFF_CAND) / (NIMG * 8);
    int cap = (int)(avail < CAPMAX ? (avail > 0 ? avail : 1) : CAPMAX);

    hipMemsetAsync(cnt, 0, NIMG * CNT_STRIDE * 4, stream);
    k_decode<<<NIMG * TILEB, 64, 0, stream>>>(logits, rel, priors, tsz,
                                              boxes, cand, cnt, cap);
    k_select<<<NIMG, 1024, 0, stream>>>(cand, cnt, topk, cap);
    k_prep<<<NIMG, 1024, 0, stream>>>(topk, boxes, cscore, clabel, cbox, coffs,
                                      carea, validw);
    k_iou<<<NIMG * 16, 1024, 0, stream>>>(coffs, carea, mask);
    k_nms<<<NIMG, 64, 0, stream>>>(mask, validw, cscore, clabel, cbox, out);
}

// Round 4
// 252.908 us; speedup vs baseline: 7.2343x; 1.1576x over previous
//
#include <hip/hip_runtime.h>
#include <math.h>

#pragma clang fp contract(off)

#define NIMG 16
#define NP   8732
#define NCLS 81
#define NFG  80
#define KTOP 1000
#define KPAD 1024
#define DETS 100
#define CAPMAX 166912          // >= 19*8732 (hard bound: <=19 softmax scores can exceed 0.05)
#define BASEBITS 0x3D000000u   // float bits of 0.03125, below 0.05 threshold; low 13 bits zero
#define CNT_STRIDE 64          // u32 units -> 256 B per image counter (own cacheline)
#define TILEB 137              // blocks per image in k_decode (137*64 >= 8732)

// ---- workspace layout (bytes) ----
#define OFF_BOXES  0u            // [NIMG][NP][4] f32  = 2,235,392
#define OFF_CNT    2235392u      // [NIMG] u32 padded to 256B each = 4096
#define OFF_TOPK   2239488u      // (unused since R4; kept for layout stability)
#define OFF_CSCORE 2370560u      // [NIMG][KPAD] f32
#define OFF_CLABEL 2436096u      // [NIMG][KPAD] i32
#define OFF_CBOX   2501632u      // [NIMG][KPAD] float4
#define OFF_COFFS  2763776u      // [NIMG][KPAD] float4
#define OFF_CAREA  3025920u      // [NIMG][KPAD] f32
#define OFF_VALIDW 3091456u      // [NIMG][16] u64
#define OFF_MASK   3093504u      // [NIMG][KPAD][16] u64 = 2,097,152
#define OFF_CAND   5190656u      // [NIMG][cap] u64

typedef unsigned long long u64;
typedef unsigned int u32;

#define AS_GLOBAL __attribute__((address_space(1)))
#define AS_LOCAL  __attribute__((address_space(3)))

// ============================================================ kernel 1
// thread-per-prior, FLAT LDS staging via async global_load_lds (width 16).
// R3's transposed scalar staging serialized on per-iteration vmcnt waits
// (~81 x 900cyc/block -> 85us at 12% VALU). Flat layout: column read
// lx[t*81+c] has odd stride 81 -> bank permutation, conflict-free.
__global__ __launch_bounds__(64, 2) void k_decode(
    const float* __restrict__ logits, const float* __restrict__ rel,
    const float* __restrict__ priors, const int* __restrict__ tsz,
    float* __restrict__ boxes_out, u64* __restrict__ cand,
    u32* __restrict__ cnt, int cap)
{
#pragma clang fp contract(off)
    __shared__ float lx[64 * NCLS];               // 20,736 B flat [prior][class]
    int b  = blockIdx.x / TILEB;
    int g  = blockIdx.x - b * TILEB;
    int p0 = g * 64;
    int t  = threadIdx.x;                          // single wave
    int npri = NP - p0; if (npri > 64) npri = 64;  // 64, or 28 in tail block
    int words = npri * NCLS;                       // multiple of 4

    // ---- async staging: all chunks queued before one barrier ----
    const u32* s32 = (const u32*)(logits + ((size_t)b * NP + p0) * NCLS); // 16B-aligned
    u32* lxw = (u32*)lx;
    int full = words >> 8;                         // 1KB chunks (64 lanes x 16 B)
    for (int k = 0; k < full; ++k)
        __builtin_amdgcn_global_load_lds(
            (AS_GLOBAL const u32*)(s32 + (k << 8) + (t << 2)),
            (AS_LOCAL u32*)(lxw + (k << 8)), 16, 0, 0);
    int base = full << 8;
    int c4 = (words - base) >> 6;                  // 256B chunks (64 lanes x 4 B)
    for (int k = 0; k < c4; ++k)
        __builtin_amdgcn_global_load_lds(
            (AS_GLOBAL const u32*)(s32 + base + (k << 6) + t),
            (AS_LOCAL u32*)(lxw + base + (k << 6)), 4, 0, 0);
    base += c4 << 6;
    if (t < words - base) lxw[base + t] = s32[base + t];

    int p = p0 + t;
    bool active = p < NP;

    // ---- box decode (per-thread, coalesced float4) ----
    int size_ok = 0;
    if (active) {
        float4 pr = ((const float4*)priors)[p];
        float4 rl = ((const float4*)rel)[(size_t)b * NP + p];
        float W = (float)tsz[b * 2 + 1], H = (float)tsz[b * 2 + 0];
        float cx = pr.x + (rl.x * 0.1f) * pr.z;
        float cy = pr.y + (rl.y * 0.1f) * pr.w;
        float w_ = pr.z * expf(rl.z * 0.2f);
        float h_ = pr.w * expf(rl.w * 0.2f);
        float4 bx;
        bx.x = (cx - 0.5f * w_) * W; bx.y = (cy - 0.5f * h_) * H;
        bx.z = (cx + 0.5f * w_) * W; bx.w = (cy + 0.5f * h_) * H;
        ((float4*)boxes_out)[(size_t)b * NP + p] = bx;
        size_ok = ((bx.z - bx.x) >= 0.01f) && ((bx.w - bx.y) >= 0.01f);
    }
    __syncthreads();                               // drains vmcnt for the LDS DMA

    // ---- own row -> registers (conflict-free: stride 81 odd) ----
    int tb = t * NCLS;
    float x[NCLS];
    #pragma unroll
    for (int c = 0; c < NCLS; ++c) x[c] = lx[tb + c];

    float m0 = x[0], m1 = x[1], m2 = x[2], m3 = x[3];
    #pragma unroll
    for (int c = 4; c + 3 < NCLS; c += 4) {
        m0 = fmaxf(m0, x[c]);     m1 = fmaxf(m1, x[c + 1]);
        m2 = fmaxf(m2, x[c + 2]); m3 = fmaxf(m3, x[c + 3]);
    }
    m0 = fmaxf(m0, x[80]);
    float m = fmaxf(fmaxf(m0, m1), fmaxf(m2, m3));

    float s0 = 0.f, s1 = 0.f, s2 = 0.f, s3 = 0.f;
    #pragma unroll
    for (int c = 0; c + 3 < NCLS; c += 4) {
        x[c]     = expf(x[c]     - m); s0 += x[c];
        x[c + 1] = expf(x[c + 1] - m); s1 += x[c + 1];
        x[c + 2] = expf(x[c + 2] - m); s2 += x[c + 2];
        x[c + 3] = expf(x[c + 3] - m); s3 += x[c + 3];
    }
    x[80] = expf(x[80] - m); s0 += x[80];
    float s = (s0 + s1) + (s2 + s3);

    // threshold: conservative band, exact f32-div fallback only inside band.
    float hi = 0.05000075f * s;
    float lo = 0.04999925f * s;
    u64 bits_lo = 0, band_lo = 0;
    u32 bits_hi = 0, band_hi = 0;
    if (active && size_ok) {
        #pragma unroll
        for (int c = 1; c < NCLS; ++c) {
            float e = x[c];
            bool pass = e > hi;
            bool band = (!pass) && (e > lo);
            int cm1 = c - 1;
            if (cm1 < 64) {
                bits_lo |= ((u64)pass) << cm1;
                band_lo |= ((u64)band) << cm1;
            } else {
                bits_hi |= ((u32)pass) << (cm1 - 64);
                band_hi |= ((u32)band) << (cm1 - 64);
            }
        }
    }
    while (band_lo) {
        int cm1 = __builtin_ctzll(band_lo); band_lo &= band_lo - 1;
        float e = expf(lx[tb + cm1 + 1] - m);
        if (e / s > 0.05f) bits_lo |= 1ULL << cm1;
    }
    while (band_hi) {
        int j = __builtin_ctz(band_hi); band_hi &= band_hi - 1;
        float e = expf(lx[tb + j + 65] - m);
        if (e / s > 0.05f) bits_hi |= 1u << j;
    }
    int cnt_t = __popcll(bits_lo) + __popc(bits_hi);

    int pre = cnt_t;
    #pragma unroll
    for (int d = 1; d < 64; d <<= 1) {
        int o = __shfl_up(pre, d);
        if (t >= d) pre += o;
    }
    u32 wbase = 0;
    if (t == 63) wbase = (pre > 0) ? atomicAdd(cnt + b * CNT_STRIDE, (u32)pre) : 0u;
    wbase = (u32)__shfl((int)wbase, 63);
    u32 pos = wbase + (u32)(pre - cnt_t);

    u64* cb = cand + (size_t)b * cap;
    u32 flatneg = 0xFFFFFFFFu - (u32)p * NFG;
    while (bits_lo) {
        int cm1 = __builtin_ctzll(bits_lo); bits_lo &= bits_lo - 1;
        float e = expf(lx[tb + cm1 + 1] - m);
        float d = e / s;
        if ((int)pos < cap)
            cb[pos] = ((u64)__float_as_uint(d) << 32) | (u64)(flatneg - (u32)cm1);
        ++pos;
    }
    while (bits_hi) {
        int j = __builtin_ctz(bits_hi); bits_hi &= bits_hi - 1;
        int cm1 = j + 64;
        float e = expf(lx[tb + cm1 + 1] - m);
        float d = e / s;
        if ((int)pos < cap)
            cb[pos] = ((u64)__float_as_uint(d) << 32) | (u64)(flatneg - (u32)cm1);
        ++pos;
    }
}

// ============================================================ kernel 2
// exact top-1000 + (fused) prep. Histogram passes load 16 B/lane; survivor
// compaction via per-wave ballot (1 LDS atomic/wave, not 1/candidate).
__device__ __forceinline__ void suffix_find(
    u32* hist, u32* wt, u32 K, int tid,
    volatile int* outI, volatile u32* outNext)
{
    int lane = tid & 63, w = tid >> 6;
    u32 v[8]; u32 tot = 0;
    #pragma unroll
    for (int k = 0; k < 8; ++k) { v[k] = hist[tid * 8 + k]; tot += v[k]; }
    u32 ws = tot;
    #pragma unroll
    for (int d = 1; d < 64; d <<= 1) {
        u32 o = __shfl_down(ws, d);
        if (lane + d < 64) ws += o;
    }
    if (lane == 0) wt[w] = ws;
    __syncthreads();
    u32 tail = 0;
    for (int w2 = w + 1; w2 < 16; ++w2) tail += wt[w2];
    u32 after = (ws - tot) + tail;
    u32 sufk[9];
    sufk[8] = after;
    #pragma unroll
    for (int k = 7; k >= 0; --k) sufk[k] = v[k] + sufk[k + 1];
    #pragma unroll
    for (int k = 0; k < 8; ++k) {
        if (sufk[k] >= K && sufk[k + 1] < K) {
            *outI = tid * 8 + k;
            *outNext = sufk[k + 1];
        }
    }
    __syncthreads();
}

__global__ __launch_bounds__(1024) void k_select(
    const u64* __restrict__ cand, const u32* __restrict__ cnt,
    const float* __restrict__ boxes,
    float* __restrict__ cscore, int* __restrict__ clabel,
    float4* __restrict__ cbox, float4* __restrict__ coffs,
    float* __restrict__ carea, u64* __restrict__ validw, int cap)
{
#pragma clang fp contract(off)
    __shared__ u32 hist[8192];
    __shared__ u64 buf[2048];
    __shared__ u32 wt[16];
    __shared__ int sh_c, sh_i2;
    __shared__ u32 sh_nhi, sh_m, sh_dummy;
    int b = blockIdx.x, tid = threadIdx.x;
    const int nt = 1024;
    u32 n = min(cnt[b * CNT_STRIDE], (u32)cap);
    const u64* cb = cand + (size_t)b * cap;

    for (int i = tid; i < 8192; i += nt) hist[i] = 0;
    if (tid == 0) {
        sh_c = -2; sh_i2 = -2; sh_nhi = 0; sh_m = 0;
        if (n & 1) {
            u32 bits = (u32)(cb[n - 1] >> 32);
            atomicAdd(&hist[(bits - BASEBITS) >> 13], 1u);
        }
    }
    __syncthreads();
    u32 npair = n >> 1;                            // cb 16B-aligned (cap even)
    for (u32 i = tid; i < npair; i += nt) {
        uint4 v = ((const uint4*)cb)[i];           // keys 2i, 2i+1
        atomicAdd(&hist[(v.y - BASEBITS) >> 13], 1u);
        atomicAdd(&hist[(v.w - BASEBITS) >> 13], 1u);
    }
    __syncthreads();
    suffix_find(hist, wt, (u32)KTOP, tid, &sh_c, &sh_nhi);
    int c = sh_c;
    u32 T = 0;
    if (c >= 0) {
        u32 nhi = sh_nhi;
        __syncthreads();
        for (int i = tid; i < 8192; i += nt) hist[i] = 0;
        __syncthreads();
        if (tid == 0 && (n & 1)) {
            u32 bits = (u32)(cb[n - 1] >> 32);
            if ((int)((bits - BASEBITS) >> 13) == c) atomicAdd(&hist[bits & 0x1FFFu], 1u);
        }
        __syncthreads();
        for (u32 i = tid; i < npair; i += nt) {
            uint4 v = ((const uint4*)cb)[i];
            if ((int)((v.y - BASEBITS) >> 13) == c) atomicAdd(&hist[v.y & 0x1FFFu], 1u);
            if ((int)((v.w - BASEBITS) >> 13) == c) atomicAdd(&hist[v.w & 0x1FFFu], 1u);
        }
        __syncthreads();
        suffix_find(hist, wt, (u32)KTOP - nhi, tid, &sh_i2, &sh_dummy);
        T = (sh_i2 >= 0) ? (BASEBITS + ((u32)c << 13) + (u32)sh_i2) : 0u;
    }
    // collect survivors (>= T): per-wave ballot compaction
    u32 nr = (n + 63) & ~63u;
    int lane = tid & 63;
    for (u32 i = tid; i < nr; i += nt) {
        u64 key = (i < n) ? cb[i] : 0ULL;
        bool pick = (i < n) && ((u32)(key >> 32) >= T);
        u64 bal = __ballot(pick);
        u32 wb = 0;
        if (lane == 0 && bal) wb = atomicAdd(&sh_m, (u32)__popcll(bal));
        wb = (u32)__shfl((int)wb, 0);
        if (pick) {
            u32 pos = wb + (u32)__popcll(bal & ((1ULL << lane) - 1ULL));
            if (pos < 2048) buf[pos] = key;
        }
    }
    __syncthreads();
    u32 mm = min(sh_m, 2048u);
    for (int i = tid; i < 2048; i += nt) if ((u32)i >= mm) buf[i] = 0ULL;
    __syncthreads();
    for (int k = 2; k <= 2048; k <<= 1) {
        for (int j = k >> 1; j > 0; j >>= 1) {
            for (int i = tid; i < 2048; i += nt) {
                int ixj = i ^ j;
                if (ixj > i) {
                    u64 a = buf[i], bb = buf[ixj];
                    bool up = (i & k) == 0;
                    if (up ? (a < bb) : (a > bb)) { buf[i] = bb; buf[ixj] = a; }
                }
            }
            __syncthreads();
        }
    }
    // ---- fused prep (was k_prep): tid owns slot tid of KPAD ----
    u64 key = (tid < KTOP) ? buf[tid] : 0ULL;
    float s = __uint_as_float((u32)(key >> 32));
    bool valid = s > 0.0f;
    u32 flat = valid ? (0xFFFFFFFFu - (u32)key) : 0u;
    int prior = (int)(flat / NFG);
    int cls = (int)(flat - (u32)prior * NFG) + 1;
    float4 bx = make_float4(0.f, 0.f, 0.f, 0.f);
    if (valid) bx = ((const float4*)boxes)[b * NP + prior];
    cscore[b * KPAD + tid] = s;
    clabel[b * KPAD + tid] = cls;
    cbox[b * KPAD + tid] = bx;
    u64 vb = __ballot(valid);
    if (lane == 0) validw[b * 16 + (tid >> 6)] = vb;
    float* red = (float*)hist;                     // reuse (hist dead after sort)
    float lm = valid ? fmaxf(fmaxf(bx.x, bx.y), fmaxf(bx.z, bx.w)) : 0.0f;
    red[tid] = fmaxf(lm, 0.0f);
    __syncthreads();
    for (int d = 512; d > 0; d >>= 1) {
        if (tid < d) red[tid] = fmaxf(red[tid], red[tid + d]);
        __syncthreads();
    }
    float mc = red[0];
    float off = (float)cls * (mc + 1.0f);
    float4 ob = valid ? make_float4(bx.x + off, bx.y + off, bx.z + off, bx.w + off)
                      : make_float4(0.f, 0.f, 0.f, 0.f);
    float area = valid ? (ob.z - ob.x) * (ob.w - ob.y) : 0.0f;
    coffs[b * KPAD + tid] = ob;
    carea[b * KPAD + tid] = area;
}

// ============================================================ kernel 4
// suppression bitmask: lane-per-row, wave-uniform column loop (LDS broadcast)
__global__ __launch_bounds__(1024) void k_iou(
    const float4* __restrict__ coffs, const float* __restrict__ carea,
    u64* __restrict__ mask)
{
#pragma clang fp contract(off)
    __shared__ float4 bs[KPAD];
    __shared__ float as_[KPAD];
    int b = blockIdx.x >> 4, tile = blockIdx.x & 15;
    int t = threadIdx.x;
    bs[t] = coffs[b * KPAD + t];
    as_[t] = carea[b * KPAD + t];
    __syncthreads();
    int i = tile * 64 + (t & 63);
    int w = t >> 6;
    u64 bits = 0;
    if (i < KTOP) {
        float4 bi = bs[i];
        float ai = as_[i];
        int j0 = w * 64;
        #pragma unroll 4
        for (int jj = 0; jj < 64; ++jj) {
            int j = j0 + jj;
            float4 bj = bs[j];
            float aj = as_[j];
            float ltx = fmaxf(bi.x, bj.x), lty = fmaxf(bi.y, bj.y);
            float rbx = fminf(bi.z, bj.z), rby = fminf(bi.w, bj.w);
            float wx = fmaxf(rbx - ltx, 0.0f), wy = fmaxf(rby - lty, 0.0f);
            float inter = wx * wy;
            float denom = ((ai + aj) - inter) + 1e-9f;
            float iou = inter / denom;
            bool sup = (iou > 0.45f) && (j > i) && (j < KTOP);
            bits |= ((u64)sup) << jj;
        }
    }
    mask[((size_t)b * KPAD + i) * 16 + w] = bits;
}

// ============================================================ kernel 5
// serial greedy NMS scan (hierarchical, one wave per image) + emit top-100
__global__ __launch_bounds__(64) void k_nms(
    const u64* __restrict__ mask, const u64* __restrict__ validw,
    const float* __restrict__ cscore, const int* __restrict__ clabel,
    const float4* __restrict__ cbox, float* __restrict__ out)
{
    int b = blockIdx.x, lane = threadIdx.x;
    const u64* mk = mask + (size_t)b * KPAD * 16;
    u64 removed = 0;
    u64 vw = (lane < 16) ? validw[b * 16 + lane] : 0ULL;
    u64 keptw = 0;
    int w = lane & 15, kb = lane >> 4;
    for (int g = 0; g < 16; ++g) {
        int row = g * 64 + lane;
        u64 wself = (row < KTOP) ? mk[row * 16 + g] : 0ULL;
        u64 part[16];
        #pragma unroll
        for (int m = 0; m < 16; ++m) {
            int r2 = g * 64 + kb + (m << 2);
            part[m] = (r2 < KTOP) ? mk[r2 * 16 + w] : 0ULL;
        }
        u64 rg = __shfl(removed, g);
        u64 vg = __shfl(vw, g);
        u64 km = 0;
        for (int k = 0; k < 64; ++k) {
            u64 wk = __shfl(wself, k);
            bool keep = ((vg >> k) & 1ULL) && !((rg >> k) & 1ULL);
            if (keep) { rg |= wk; km |= 1ULL << k; }
        }
        u64 acc = 0;
        #pragma unroll
        for (int m = 0; m < 16; ++m) {
            int k = kb + (m << 2);
            if ((km >> k) & 1ULL) acc |= part[m];
        }
        acc |= __shfl_xor(acc, 16);
        acc |= __shfl_xor(acc, 32);
        if (lane < 16) removed |= acc;
        if (lane == g) { removed |= rg; keptw = km; }
    }
    __shared__ u64 sk[16];
    __shared__ int pfx[17];
    __shared__ int slot[DETS];
    if (lane < 16) sk[lane] = keptw & vw & ~removed;
    __syncthreads();
    if (lane == 0) {
        int run = 0;
        for (int l = 0; l < 16; ++l) { pfx[l] = run; run += __popcll(sk[l]); }
        pfx[16] = run;
    }
    __syncthreads();
    if (lane < 16) {
        int r = pfx[lane];
        u64 wv = sk[lane];
        while (wv && r < DETS) {
            int bit = __builtin_ctzll(wv);
            slot[r] = lane * 64 + bit;
            ++r;
            wv &= wv - 1;
        }
    }
    __syncthreads();
    int total = min(pfx[16], DETS);
    for (int r = lane; r < DETS; r += 64) {
        float4 bx = make_float4(0.f, 0.f, 0.f, 0.f);
        float s = 0.0f;
        int lb = -1;
        if (r < total) {
            int cdx = slot[r];
            bx = cbox[b * KPAD + cdx];
            s = cscore[b * KPAD + cdx];
            lb = clabel[b * KPAD + cdx];
        }
        float* ob = out + ((size_t)b * DETS + r) * 4;
        ob[0] = bx.x; ob[1] = bx.y; ob[2] = bx.z; ob[3] = bx.w;
        out[NIMG * DETS * 4 + b * DETS + r] = s;
        out[NIMG * DETS * 4 + NIMG * DETS + b * DETS + r] = (float)lb;
    }
}

// ============================================================ launch
extern "C" void kernel_launch(void* const* d_in, const int* in_sizes, int n_in,
                              void* d_out, int out_size, void* d_ws, size_t ws_size,
                              hipStream_t stream) {
    const float* logits = (const float*)d_in[0];
    const float* rel    = (const float*)d_in[1];
    const float* priors = (const float*)d_in[2];
    const int*   tsz    = (const int*)d_in[3];
    float* out = (float*)d_out;
    char* ws = (char*)d_ws;

    float* boxes  = (float*)(ws + OFF_BOXES);
    u32*   cnt    = (u32*)(ws + OFF_CNT);
    float* cscore = (float*)(ws + OFF_CSCORE);
    int*   clabel = (int*)(ws + OFF_CLABEL);
    float4* cbox  = (float4*)(ws + OFF_CBOX);
    float4* coffs = (float4*)(ws + OFF_COFFS);
    float* carea  = (float*)(ws + OFF_CAREA);
    u64*   validw = (u64*)(ws + OFF_VALIDW);
    u64*   mask   = (u64*)(ws + OFF_MASK);
    u64*   cand   = (u64*)(ws + OFF_CAND);

    long long avail = ((long long)ws_size - (long long)OFF_CAND) / (NIMG * 8);
    int cap = (int)(avail < CAPMAX ? (avail > 0 ? avail : 1) : CAPMAX);
    cap &= ~1;                                    // even -> 16B-aligned per-image base

    hipMemsetAsync(cnt, 0, NIMG * CNT_STRIDE * 4, stream);
    k_decode<<<NIMG * TILEB, 64, 0, stream>>>(logits, rel, priors, tsz,
                                              boxes, cand, cnt, cap);
    k_select<<<NIMG, 1024, 0, stream>>>(cand, cnt, boxes, cscore, clabel,
                                        cbox, coffs, carea, validw, cap);
    k_iou<<<NIMG * 16, 1024, 0, stream>>>(coffs, carea, mask);
    k_nms<<<NIMG, 64, 0, stream>>>(mask, validw, cscore, clabel, cbox, out);
}

// Round 5
// 191.723 us; speedup vs baseline: 9.5429x; 1.3191x over previous
//
#include <hip/hip_runtime.h>
#include <math.h>

#pragma clang fp contract(off)

#define NIMG 16
#define NP   8732
#define NCLS 81
#define NFG  80
#define KTOP 1000
#define KPAD 1024
#define DETS 100
#define CAPMAX 166912          // >= 19*8732 (hard bound: <=19 softmax scores can exceed 0.05)
#define BASEBITS 0x3D000000u   // float bits of 0.03125, below 0.05 threshold; low 13 bits zero
#define CNT_STRIDE 64          // u32 units -> 256 B per image counter (own cacheline)
#define TILEB 137              // blocks per image in k_decode (137*64 >= 8732)

// ---- workspace layout (bytes) ----
#define OFF_BOXES  0u            // [NIMG][NP][4] f32  = 2,235,392
#define OFF_CNT    2235392u      // [NIMG] u32 padded to 256B each = 4096
#define OFF_TOPK   2239488u      // (unused; kept for layout stability)
#define OFF_CSCORE 2370560u      // [NIMG][KPAD] f32
#define OFF_CLABEL 2436096u      // [NIMG][KPAD] i32
#define OFF_CBOX   2501632u      // [NIMG][KPAD] float4
#define OFF_COFFS  2763776u      // [NIMG][KPAD] float4
#define OFF_CAREA  3025920u      // [NIMG][KPAD] f32
#define OFF_VALIDW 3091456u      // [NIMG][16] u64
#define OFF_MASK   3093504u      // [NIMG][16][KPAD] u64 column-major = 2,097,152
#define OFF_CAND   5190656u      // [NIMG][cap] u64

typedef unsigned long long u64;
typedef unsigned int u32;

#define AS_GLOBAL __attribute__((address_space(1)))
#define AS_LOCAL  __attribute__((address_space(3)))

// ============================================================ kernel 1
// thread-per-prior, FLAT LDS staging via async global_load_lds (width 16).
__global__ __launch_bounds__(64, 2) void k_decode(
    const float* __restrict__ logits, const float* __restrict__ rel,
    const float* __restrict__ priors, const int* __restrict__ tsz,
    float* __restrict__ boxes_out, u64* __restrict__ cand,
    u32* __restrict__ cnt, int cap)
{
#pragma clang fp contract(off)
    __shared__ float lx[64 * NCLS];               // 20,736 B flat [prior][class]
    int b  = blockIdx.x / TILEB;
    int g  = blockIdx.x - b * TILEB;
    int p0 = g * 64;
    int t  = threadIdx.x;                          // single wave
    int npri = NP - p0; if (npri > 64) npri = 64;  // 64, or 28 in tail block
    int words = npri * NCLS;                       // multiple of 4

    // ---- async staging: all chunks queued before one barrier ----
    const u32* s32 = (const u32*)(logits + ((size_t)b * NP + p0) * NCLS); // 16B-aligned
    u32* lxw = (u32*)lx;
    int full = words >> 8;                         // 1KB chunks (64 lanes x 16 B)
    for (int k = 0; k < full; ++k)
        __builtin_amdgcn_global_load_lds(
            (AS_GLOBAL const u32*)(s32 + (k << 8) + (t << 2)),
            (AS_LOCAL u32*)(lxw + (k << 8)), 16, 0, 0);
    int base = full << 8;
    int c4 = (words - base) >> 6;                  // 256B chunks (64 lanes x 4 B)
    for (int k = 0; k < c4; ++k)
        __builtin_amdgcn_global_load_lds(
            (AS_GLOBAL const u32*)(s32 + base + (k << 6) + t),
            (AS_LOCAL u32*)(lxw + base + (k << 6)), 4, 0, 0);
    base += c4 << 6;
    if (t < words - base) lxw[base + t] = s32[base + t];

    int p = p0 + t;
    bool active = p < NP;

    // ---- box decode (per-thread, coalesced float4) ----
    int size_ok = 0;
    if (active) {
        float4 pr = ((const float4*)priors)[p];
        float4 rl = ((const float4*)rel)[(size_t)b * NP + p];
        float W = (float)tsz[b * 2 + 1], H = (float)tsz[b * 2 + 0];
        float cx = pr.x + (rl.x * 0.1f) * pr.z;
        float cy = pr.y + (rl.y * 0.1f) * pr.w;
        float w_ = pr.z * expf(rl.z * 0.2f);
        float h_ = pr.w * expf(rl.w * 0.2f);
        float4 bx;
        bx.x = (cx - 0.5f * w_) * W; bx.y = (cy - 0.5f * h_) * H;
        bx.z = (cx + 0.5f * w_) * W; bx.w = (cy + 0.5f * h_) * H;
        ((float4*)boxes_out)[(size_t)b * NP + p] = bx;
        size_ok = ((bx.z - bx.x) >= 0.01f) && ((bx.w - bx.y) >= 0.01f);
    }
    __syncthreads();                               // drains vmcnt for the LDS DMA

    // ---- own row -> registers (conflict-free: stride 81 odd) ----
    int tb = t * NCLS;
    float x[NCLS];
    #pragma unroll
    for (int c = 0; c < NCLS; ++c) x[c] = lx[tb + c];

    float m0 = x[0], m1 = x[1], m2 = x[2], m3 = x[3];
    #pragma unroll
    for (int c = 4; c + 3 < NCLS; c += 4) {
        m0 = fmaxf(m0, x[c]);     m1 = fmaxf(m1, x[c + 1]);
        m2 = fmaxf(m2, x[c + 2]); m3 = fmaxf(m3, x[c + 3]);
    }
    m0 = fmaxf(m0, x[80]);
    float m = fmaxf(fmaxf(m0, m1), fmaxf(m2, m3));

    float s0 = 0.f, s1 = 0.f, s2 = 0.f, s3 = 0.f;
    #pragma unroll
    for (int c = 0; c + 3 < NCLS; c += 4) {
        x[c]     = expf(x[c]     - m); s0 += x[c];
        x[c + 1] = expf(x[c + 1] - m); s1 += x[c + 1];
        x[c + 2] = expf(x[c + 2] - m); s2 += x[c + 2];
        x[c + 3] = expf(x[c + 3] - m); s3 += x[c + 3];
    }
    x[80] = expf(x[80] - m); s0 += x[80];
    float s = (s0 + s1) + (s2 + s3);

    // threshold: conservative band, exact f32-div fallback only inside band.
    float hi = 0.05000075f * s;
    float lo = 0.04999925f * s;
    u64 bits_lo = 0, band_lo = 0;
    u32 bits_hi = 0, band_hi = 0;
    if (active && size_ok) {
        #pragma unroll
        for (int c = 1; c < NCLS; ++c) {
            float e = x[c];
            bool pass = e > hi;
            bool band = (!pass) && (e > lo);
            int cm1 = c - 1;
            if (cm1 < 64) {
                bits_lo |= ((u64)pass) << cm1;
                band_lo |= ((u64)band) << cm1;
            } else {
                bits_hi |= ((u32)pass) << (cm1 - 64);
                band_hi |= ((u32)band) << (cm1 - 64);
            }
        }
    }
    while (band_lo) {
        int cm1 = __builtin_ctzll(band_lo); band_lo &= band_lo - 1;
        float e = expf(lx[tb + cm1 + 1] - m);
        if (e / s > 0.05f) bits_lo |= 1ULL << cm1;
    }
    while (band_hi) {
        int j = __builtin_ctz(band_hi); band_hi &= band_hi - 1;
        float e = expf(lx[tb + j + 65] - m);
        if (e / s > 0.05f) bits_hi |= 1u << j;
    }
    int cnt_t = __popcll(bits_lo) + __popc(bits_hi);

    int pre = cnt_t;
    #pragma unroll
    for (int d = 1; d < 64; d <<= 1) {
        int o = __shfl_up(pre, d);
        if (t >= d) pre += o;
    }
    u32 wbase = 0;
    if (t == 63) wbase = (pre > 0) ? atomicAdd(cnt + b * CNT_STRIDE, (u32)pre) : 0u;
    wbase = (u32)__shfl((int)wbase, 63);
    u32 pos = wbase + (u32)(pre - cnt_t);

    u64* cb = cand + (size_t)b * cap;
    u32 flatneg = 0xFFFFFFFFu - (u32)p * NFG;
    while (bits_lo) {
        int cm1 = __builtin_ctzll(bits_lo); bits_lo &= bits_lo - 1;
        float e = expf(lx[tb + cm1 + 1] - m);
        float d = e / s;
        if ((int)pos < cap)
            cb[pos] = ((u64)__float_as_uint(d) << 32) | (u64)(flatneg - (u32)cm1);
        ++pos;
    }
    while (bits_hi) {
        int j = __builtin_ctz(bits_hi); bits_hi &= bits_hi - 1;
        int cm1 = j + 64;
        float e = expf(lx[tb + cm1 + 1] - m);
        float d = e / s;
        if ((int)pos < cap)
            cb[pos] = ((u64)__float_as_uint(d) << 32) | (u64)(flatneg - (u32)cm1);
        ++pos;
    }
}

// ============================================================ kernel 2
// exact top-1000 + fused prep (histogram select, bitonic sort, gather).
__device__ __forceinline__ void suffix_find(
    u32* hist, u32* wt, u32 K, int tid,
    volatile int* outI, volatile u32* outNext)
{
    int lane = tid & 63, w = tid >> 6;
    u32 v[8]; u32 tot = 0;
    #pragma unroll
    for (int k = 0; k < 8; ++k) { v[k] = hist[tid * 8 + k]; tot += v[k]; }
    u32 ws = tot;
    #pragma unroll
    for (int d = 1; d < 64; d <<= 1) {
        u32 o = __shfl_down(ws, d);
        if (lane + d < 64) ws += o;
    }
    if (lane == 0) wt[w] = ws;
    __syncthreads();
    u32 tail = 0;
    for (int w2 = w + 1; w2 < 16; ++w2) tail += wt[w2];
    u32 after = (ws - tot) + tail;
    u32 sufk[9];
    sufk[8] = after;
    #pragma unroll
    for (int k = 7; k >= 0; --k) sufk[k] = v[k] + sufk[k + 1];
    #pragma unroll
    for (int k = 0; k < 8; ++k) {
        if (sufk[k] >= K && sufk[k + 1] < K) {
            *outI = tid * 8 + k;
            *outNext = sufk[k + 1];
        }
    }
    __syncthreads();
}

__global__ __launch_bounds__(1024) void k_select(
    const u64* __restrict__ cand, const u32* __restrict__ cnt,
    const float* __restrict__ boxes,
    float* __restrict__ cscore, int* __restrict__ clabel,
    float4* __restrict__ cbox, float4* __restrict__ coffs,
    float* __restrict__ carea, u64* __restrict__ validw, int cap)
{
#pragma clang fp contract(off)
    __shared__ u32 hist[8192];
    __shared__ u64 buf[2048];
    __shared__ u32 wt[16];
    __shared__ int sh_c, sh_i2;
    __shared__ u32 sh_nhi, sh_m, sh_dummy;
    int b = blockIdx.x, tid = threadIdx.x;
    const int nt = 1024;
    u32 n = min(cnt[b * CNT_STRIDE], (u32)cap);
    const u64* cb = cand + (size_t)b * cap;

    for (int i = tid; i < 8192; i += nt) hist[i] = 0;
    if (tid == 0) {
        sh_c = -2; sh_i2 = -2; sh_nhi = 0; sh_m = 0;
        if (n & 1) {
            u32 bits = (u32)(cb[n - 1] >> 32);
            atomicAdd(&hist[(bits - BASEBITS) >> 13], 1u);
        }
    }
    __syncthreads();
    u32 npair = n >> 1;                            // cb 16B-aligned (cap even)
    for (u32 i = tid; i < npair; i += nt) {
        uint4 v = ((const uint4*)cb)[i];           // keys 2i, 2i+1
        atomicAdd(&hist[(v.y - BASEBITS) >> 13], 1u);
        atomicAdd(&hist[(v.w - BASEBITS) >> 13], 1u);
    }
    __syncthreads();
    suffix_find(hist, wt, (u32)KTOP, tid, &sh_c, &sh_nhi);
    int c = sh_c;
    u32 T = 0;
    if (c >= 0) {
        u32 nhi = sh_nhi;
        __syncthreads();
        for (int i = tid; i < 8192; i += nt) hist[i] = 0;
        __syncthreads();
        if (tid == 0 && (n & 1)) {
            u32 bits = (u32)(cb[n - 1] >> 32);
            if ((int)((bits - BASEBITS) >> 13) == c) atomicAdd(&hist[bits & 0x1FFFu], 1u);
        }
        __syncthreads();
        for (u32 i = tid; i < npair; i += nt) {
            uint4 v = ((const uint4*)cb)[i];
            if ((int)((v.y - BASEBITS) >> 13) == c) atomicAdd(&hist[v.y & 0x1FFFu], 1u);
            if ((int)((v.w - BASEBITS) >> 13) == c) atomicAdd(&hist[v.w & 0x1FFFu], 1u);
        }
        __syncthreads();
        suffix_find(hist, wt, (u32)KTOP - nhi, tid, &sh_i2, &sh_dummy);
        T = (sh_i2 >= 0) ? (BASEBITS + ((u32)c << 13) + (u32)sh_i2) : 0u;
    }
    // collect survivors (>= T): per-wave ballot compaction
    u32 nr = (n + 63) & ~63u;
    int lane = tid & 63;
    for (u32 i = tid; i < nr; i += nt) {
        u64 key = (i < n) ? cb[i] : 0ULL;
        bool pick = (i < n) && ((u32)(key >> 32) >= T);
        u64 bal = __ballot(pick);
        u32 wb = 0;
        if (lane == 0 && bal) wb = atomicAdd(&sh_m, (u32)__popcll(bal));
        wb = (u32)__shfl((int)wb, 0);
        if (pick) {
            u32 pos = wb + (u32)__popcll(bal & ((1ULL << lane) - 1ULL));
            if (pos < 2048) buf[pos] = key;
        }
    }
    __syncthreads();
    u32 mm = min(sh_m, 2048u);
    for (int i = tid; i < 2048; i += nt) if ((u32)i >= mm) buf[i] = 0ULL;
    __syncthreads();
    for (int k = 2; k <= 2048; k <<= 1) {
        for (int j = k >> 1; j > 0; j >>= 1) {
            for (int i = tid; i < 2048; i += nt) {
                int ixj = i ^ j;
                if (ixj > i) {
                    u64 a = buf[i], bb = buf[ixj];
                    bool up = (i & k) == 0;
                    if (up ? (a < bb) : (a > bb)) { buf[i] = bb; buf[ixj] = a; }
                }
            }
            __syncthreads();
        }
    }
    // ---- fused prep: tid owns slot tid of KPAD ----
    u64 key = (tid < KTOP) ? buf[tid] : 0ULL;
    float s = __uint_as_float((u32)(key >> 32));
    bool valid = s > 0.0f;
    u32 flat = valid ? (0xFFFFFFFFu - (u32)key) : 0u;
    int prior = (int)(flat / NFG);
    int cls = (int)(flat - (u32)prior * NFG) + 1;
    float4 bx = make_float4(0.f, 0.f, 0.f, 0.f);
    if (valid) bx = ((const float4*)boxes)[b * NP + prior];
    cscore[b * KPAD + tid] = s;
    clabel[b * KPAD + tid] = cls;
    cbox[b * KPAD + tid] = bx;
    u64 vb = __ballot(valid);
    if (lane == 0) validw[b * 16 + (tid >> 6)] = vb;
    float* red = (float*)hist;                     // reuse (hist dead after sort)
    float lm = valid ? fmaxf(fmaxf(bx.x, bx.y), fmaxf(bx.z, bx.w)) : 0.0f;
    red[tid] = fmaxf(lm, 0.0f);
    __syncthreads();
    for (int d = 512; d > 0; d >>= 1) {
        if (tid < d) red[tid] = fmaxf(red[tid], red[tid + d]);
        __syncthreads();
    }
    float mc = red[0];
    float off = (float)cls * (mc + 1.0f);
    float4 ob = valid ? make_float4(bx.x + off, bx.y + off, bx.z + off, bx.w + off)
                      : make_float4(0.f, 0.f, 0.f, 0.f);
    float area = valid ? (ob.z - ob.x) * (ob.w - ob.y) : 0.0f;
    coffs[b * KPAD + tid] = ob;
    carea[b * KPAD + tid] = area;
}

// ============================================================ kernel 4
// suppression bitmask, COLUMN-major: cmask[b][w][j] bit k = row (64w+k)
// suppresses column j. Lane owns column j; row reads are wave-uniform LDS
// broadcasts. Coalesced writes (consecutive j -> consecutive u64).
__global__ __launch_bounds__(1024) void k_iou(
    const float4* __restrict__ coffs, const float* __restrict__ carea,
    u64* __restrict__ cmask)
{
#pragma clang fp contract(off)
    __shared__ float4 bs[KPAD];
    __shared__ float as_[KPAD];
    int b = blockIdx.x >> 4, tile = blockIdx.x & 15;
    int t = threadIdx.x;
    bs[t] = coffs[b * KPAD + t];
    as_[t] = carea[b * KPAD + t];
    __syncthreads();
    int j = tile * 64 + (t & 63);                  // column (suppressee)
    int w = t >> 6;                                // row word
    float4 bj = bs[j];
    float aj = as_[j];
    int r0 = w * 64;
    u64 bits = 0;
    #pragma unroll 4
    for (int k = 0; k < 64; ++k) {
        int r = r0 + k;                            // wave-uniform row
        float4 br = bs[r];
        float ar = as_[r];
        float ltx = fmaxf(br.x, bj.x), lty = fmaxf(br.y, bj.y);
        float rbx = fminf(br.z, bj.z), rby = fminf(br.w, bj.w);
        float wx = fmaxf(rbx - ltx, 0.0f), wy = fmaxf(rby - lty, 0.0f);
        float inter = wx * wy;
        float denom = ((ar + aj) - inter) + 1e-9f;
        float iou = inter / denom;
        bool sup = (iou > 0.45f) && (j > r);
        bits |= ((u64)sup) << k;
    }
    cmask[((size_t)b * 16 + w) * KPAD + j] = bits;
}

// ============================================================ kernel 5
// NMS via ballot fixpoint. Greedy kept-set is the unique fixpoint of
// F(K) = { j : valid_j and K∩col_j=∅ } (cols well-founded: bits only k<j).
// Antitone squeeze => iteration K<-F(K) terminates at it (typ. <5 iters).
// No shfl/LDS in the resolve; next group's columns prefetched (coalesced).
__global__ __launch_bounds__(64) void k_nms(
    const u64* __restrict__ cmask, const u64* __restrict__ validw,
    const float* __restrict__ cscore, const int* __restrict__ clabel,
    const float4* __restrict__ cbox, float* __restrict__ out)
{
    int b = blockIdx.x, lane = threadIdx.x;
    const u64* cm = cmask + (size_t)b * 16 * KPAD;
    u64 kept[16];
    u64 cw[16];
    #pragma unroll
    for (int w = 0; w < 16; ++w) cw[w] = cm[w * KPAD + lane];   // group 0 cols
    #pragma unroll
    for (int g = 0; g < 16; ++g) {
        u64 vg = validw[b * 16 + g];
        bool rem = false;
        #pragma unroll
        for (int w = 0; w < 16; ++w)
            if (w < g) rem |= (kept[w] & cw[w]) != 0ULL;
        u64 cg = cw[g];
        bool myv = ((vg >> lane) & 1ULL) && !rem;
        if (g < 15) {                               // prefetch next group's cols
            int cbase = (g + 1) * 64 + lane;
            #pragma unroll
            for (int w = 0; w < 16; ++w) cw[w] = cm[w * KPAD + cbase];
        }
        u64 K = __ballot(myv);
        for (;;) {
            u64 K2 = __ballot(myv && ((K & cg) == 0ULL));
            if (K2 == K) break;
            K = K2;
        }
        kept[g] = K;                                // wave-uniform
    }
    __shared__ u64 sk[16];
    __shared__ int pfx[17];
    __shared__ int slot[DETS];
    if (lane == 0) {
        #pragma unroll
        for (int w = 0; w < 16; ++w) sk[w] = kept[w];
        int run = 0;
        #pragma unroll
        for (int l = 0; l < 16; ++l) { pfx[l] = run; run += __popcll(kept[l]); }
        pfx[16] = run;
    }
    __syncthreads();
    if (lane < 16) {
        int r = pfx[lane];
        u64 wv = sk[lane];
        while (wv && r < DETS) {
            int bit = __builtin_ctzll(wv);
            slot[r] = lane * 64 + bit;
            ++r;
            wv &= wv - 1;
        }
    }
    __syncthreads();
    int total = min(pfx[16], DETS);
    for (int r = lane; r < DETS; r += 64) {
        float4 bx = make_float4(0.f, 0.f, 0.f, 0.f);
        float s = 0.0f;
        int lb = -1;
        if (r < total) {
            int cdx = slot[r];
            bx = cbox[b * KPAD + cdx];
            s = cscore[b * KPAD + cdx];
            lb = clabel[b * KPAD + cdx];
        }
        float* ob = out + ((size_t)b * DETS + r) * 4;
        ob[0] = bx.x; ob[1] = bx.y; ob[2] = bx.z; ob[3] = bx.w;
        out[NIMG * DETS * 4 + b * DETS + r] = s;
        out[NIMG * DETS * 4 + NIMG * DETS + b * DETS + r] = (float)lb;
    }
}

// ============================================================ launch
extern "C" void kernel_launch(void* const* d_in, const int* in_sizes, int n_in,
                              void* d_out, int out_size, void* d_ws, size_t ws_size,
                              hipStream_t stream) {
    const float* logits = (const float*)d_in[0];
    const float* rel    = (const float*)d_in[1];
    const float* priors = (const float*)d_in[2];
    const int*   tsz    = (const int*)d_in[3];
    float* out = (float*)d_out;
    char* ws = (char*)d_ws;

    float* boxes  = (float*)(ws + OFF_BOXES);
    u32*   cnt    = (u32*)(ws + OFF_CNT);
    float* cscore = (float*)(ws + OFF_CSCORE);
    int*   clabel = (int*)(ws + OFF_CLABEL);
    float4* cbox  = (float4*)(ws + OFF_CBOX);
    float4* coffs = (float4*)(ws + OFF_COFFS);
    float* carea  = (float*)(ws + OFF_CAREA);
    u64*   validw = (u64*)(ws + OFF_VALIDW);
    u64*   cmask  = (u64*)(ws + OFF_MASK);
    u64*   cand   = (u64*)(ws + OFF_CAND);

    long long avail = ((long long)ws_size - (long long)OFF_CAND) / (NIMG * 8);
    int cap = (int)(avail < CAPMAX ? (avail > 0 ? avail : 1) : CAPMAX);
    cap &= ~1;                                    // even -> 16B-aligned per-image base

    hipMemsetAsync(cnt, 0, NIMG * CNT_STRIDE * 4, stream);
    k_decode<<<NIMG * TILEB, 64, 0, stream>>>(logits, rel, priors, tsz,
                                              boxes, cand, cnt, cap);
    k_select<<<NIMG, 1024, 0, stream>>>(cand, cnt, boxes, cscore, clabel,
                                        cbox, coffs, carea, validw, cap);
    k_iou<<<NIMG * 16, 1024, 0, stream>>>(coffs, carea, cmask);
    k_nms<<<NIMG, 64, 0, stream>>>(cmask, validw, cscore, clabel, cbox, out);
}